// Round 7
// baseline (5520.907 us; speedup 1.0000x reference)
//
#include <hip/hip_runtime.h>

#define ATB_B 256
#define WROWS 8192   // rows per CSR-build window (32KB LDS of int)

// ===========================================================================
// Windowed 3-graph CSR build — NO global atomics (round-6 lesson: 3M random
// 8B writes/4B atomics = 3M x 64B line traffic = 192MB -> 240us each).
// One block per (graph, 8192-row window); counts/cursors live in LDS.
// ===========================================================================
__global__ __launch_bounds__(256) void hist_w(const int* __restrict__ rA,
                                              const int* __restrict__ rT,
                                              const int* __restrict__ rU,
                                              int nnzA, int nnzU,
                                              int* __restrict__ cntAll,
                                              int U, int I, int wU, int wI) {
    int b = blockIdx.x;
    const int* rows; int nnz, n, coff, w;
    if (b < wU)           { rows = rA; nnz = nnzA; n = U; coff = 0;     w = b; }
    else if (b < wU + wI) { rows = rT; nnz = nnzA; n = I; coff = U;     w = b - wU; }
    else                  { rows = rU; nnz = nnzU; n = U; coff = U + I; w = b - wU - wI; }
    int w0 = w * WROWS;
    int wend = w0 + WROWS; if (wend > n) wend = n;
    int wlen = wend - w0;
    __shared__ int cnt[WROWS];
    int tid = threadIdx.x;
    for (int i = tid; i < WROWS; i += 256) cnt[i] = 0;
    __syncthreads();
    for (int i = tid; i < nnz; i += 256) {
        int r = rows[i];
        if (r >= w0 && r < wend) atomicAdd(&cnt[r - w0], 1);
    }
    __syncthreads();
    for (int i = tid; i < wlen; i += 256) cntAll[coff + w0 + i] = cnt[i];
}

// per-256-chunk sums, 3 segments
__global__ __launch_bounds__(256) void scan_part3(const int* __restrict__ cntAll,
                                                  int* __restrict__ bsumAll,
                                                  int U, int I, int nbA, int nbT) {
    int b = blockIdx.x;
    int lb, n, coff, bsoff;
    if (b < nbA)            { lb = b;             n = U; coff = 0;     bsoff = 0; }
    else if (b < nbA + nbT) { lb = b - nbA;       n = I; coff = U;     bsoff = 1024; }
    else                    { lb = b - nbA - nbT; n = U; coff = U + I; bsoff = 2048; }
    __shared__ int sh[256];
    int tid = threadIdx.x;
    int i = lb * 256 + tid;
    sh[tid] = (i < n) ? cntAll[coff + i] : 0;
    __syncthreads();
    for (int st = 128; st > 0; st >>= 1) {
        if (tid < st) sh[tid] += sh[tid + st];
        __syncthreads();
    }
    if (tid == 0) bsumAll[bsoff + lb] = sh[0];
}

// exclusive scan of block sums: 3 blocks, one per graph
__global__ __launch_bounds__(1024) void scan_top3(int* __restrict__ bsumAll,
                                                  int nbA, int nbT, int nbU) {
    int g = blockIdx.x;
    int nb = (g == 0) ? nbA : (g == 1 ? nbT : nbU);
    int* b = bsumAll + g * 1024;
    __shared__ int sh[1024];
    int tid = threadIdx.x;
    int orig = (tid < nb) ? b[tid] : 0;
    sh[tid] = orig;
    __syncthreads();
    for (int st = 1; st < 1024; st <<= 1) {
        int v = (tid >= st) ? sh[tid - st] : 0;
        __syncthreads();
        sh[tid] += v;
        __syncthreads();
    }
    if (tid < nb) b[tid] = sh[tid] - orig;
}

// in-block exclusive scan + block offset -> rp (curAll holds counts in)
__global__ __launch_bounds__(256) void scan_final3(int* __restrict__ curAll,
                                                   const int* __restrict__ bsumAll,
                                                   int* __restrict__ rpAll,
                                                   int U, int I, int nbA, int nbT,
                                                   int nnzA, int nnzU) {
    int b = blockIdx.x;
    int lb, n, coff, bsoff, rpoff, nnz;
    if (b < nbA)            { lb = b;             n = U; coff = 0;     bsoff = 0;    rpoff = 0;                 nnz = nnzA; }
    else if (b < nbA + nbT) { lb = b - nbA;       n = I; coff = U;     bsoff = 1024; rpoff = U + 1;             nnz = nnzA; }
    else                    { lb = b - nbA - nbT; n = U; coff = U + I; bsoff = 2048; rpoff = (U + 1) + (I + 1); nnz = nnzU; }
    __shared__ int sh[256];
    int tid = threadIdx.x;
    int i = lb * 256 + tid;
    int orig = (i < n) ? curAll[coff + i] : 0;
    sh[tid] = orig;
    __syncthreads();
    for (int st = 1; st < 256; st <<= 1) {
        int v = (tid >= st) ? sh[tid - st] : 0;
        __syncthreads();
        sh[tid] += v;
        __syncthreads();
    }
    int ex = sh[tid] - orig + bsumAll[bsoff + lb];
    if (i < n) rpAll[rpoff + i] = ex;
    if (i == n - 1) rpAll[rpoff + n] = nnz;
}

// windowed scatter: LDS cursors (seeded from rp), LDS atomics only; edge
// writes land in the window's contiguous ~650KB CSR region (L2-resident).
__global__ __launch_bounds__(256) void scatter_w(const int* __restrict__ rA, const int* __restrict__ cA, const float* __restrict__ vA,
                                                 const int* __restrict__ rT, const int* __restrict__ cT, const float* __restrict__ vT,
                                                 const int* __restrict__ rU, const int* __restrict__ cU, const float* __restrict__ vU,
                                                 const int* __restrict__ rpAll, int2* __restrict__ eAll,
                                                 int nnzA, int nnzU, int U, int I, int wU, int wI) {
    int b = blockIdx.x;
    const int* rows; const int* cols; const float* vals;
    int nnz, n, rpoff, w; size_t ebase;
    if (b < wU)           { rows = rA; cols = cA; vals = vA; nnz = nnzA; n = U; rpoff = 0;                 ebase = 0;            w = b; }
    else if (b < wU + wI) { rows = rT; cols = cT; vals = vT; nnz = nnzA; n = I; rpoff = U + 1;             ebase = nnzA;         w = b - wU; }
    else                  { rows = rU; cols = cU; vals = vU; nnz = nnzU; n = U; rpoff = (U + 1) + (I + 1); ebase = 2 * (size_t)nnzA; w = b - wU - wI; }
    int w0 = w * WROWS;
    int wend = w0 + WROWS; if (wend > n) wend = n;
    int wlen = wend - w0;
    __shared__ int cur[WROWS];
    int tid = threadIdx.x;
    for (int i = tid; i < wlen; i += 256) cur[i] = rpAll[rpoff + w0 + i];
    __syncthreads();
    for (int i = tid; i < nnz; i += 256) {
        int r = rows[i];
        if (r >= w0 && r < wend) {
            int p = atomicAdd(&cur[r - w0], 1);
            eAll[ebase + p] = make_int2(cols[i], __float_as_int(vals[i]));
        }
    }
}

// ===========================================================================
// Multi-segment gather SpMM: one wave per output row, lane = column d.
// out = gather(row) [+ a0] [+ a1]
// ===========================================================================
struct Seg { const int* rp; const int2* eg; const float* X; const float* a0; const float* a1; float* out; int N; };
struct Spmm3Args { Seg s0, s1, s2; int n0, n01, total; };

__global__ __launch_bounds__(256) void spmm3(Spmm3Args A) {
    int gid = blockIdx.x * 256 + threadIdx.x;
    int r = gid >> 6;
    if (r >= A.total) return;
    int d = gid & 63;
    Seg sg; int lr;
    if (r < A.n0)       { sg = A.s0; lr = r; }
    else if (r < A.n01) { sg = A.s1; lr = r - A.n0; }
    else                { sg = A.s2; lr = r - A.n01; }
    int s = sg.rp[lr], e = sg.rp[lr + 1];
    const float* __restrict__ X = sg.X;
    float acc = 0.f;
    int i = s;
    for (; i + 4 <= e; i += 4) {
        int2 e0 = sg.eg[i], e1 = sg.eg[i + 1], e2 = sg.eg[i + 2], e3 = sg.eg[i + 3];
        float x0 = X[(size_t)e0.x * 64 + d];
        float x1 = X[(size_t)e1.x * 64 + d];
        float x2 = X[(size_t)e2.x * 64 + d];
        float x3 = X[(size_t)e3.x * 64 + d];
        acc += __int_as_float(e0.y) * x0;
        acc += __int_as_float(e1.y) * x1;
        acc += __int_as_float(e2.y) * x2;
        acc += __int_as_float(e3.y) * x3;
    }
    for (; i < e; ++i) {
        int2 ee = sg.eg[i];
        acc += __int_as_float(ee.y) * X[(size_t)ee.x * 64 + d];
    }
    size_t o = (size_t)lr * 64 + d;
    if (sg.a0) acc += sg.a0[o];
    if (sg.a1) acc += sg.a1[o];
    sg.out[o] = acc;
}

// ===========================================================================
// Key = E @ K in (H,N,DH) layout, 3 segments (one dispatch for all graphs)
// ===========================================================================
struct KSeg { const float* E; const float* K; float* Kout; int N; };
struct Key3Args { KSeg s0, s1, s2; int b1, b2; };

__global__ __launch_bounds__(256) void key3(Key3Args A) {
    int b = blockIdx.x;
    KSeg sg; int lb;
    if (b >= A.b2)      { sg = A.s2; lb = b - A.b2; }
    else if (b >= A.b1) { sg = A.s1; lb = b - A.b1; }
    else                { sg = A.s0; lb = b; }
    __shared__ float Ksh[4096];
    int tid = threadIdx.x;
    for (int i = tid; i < 4096; i += 256) Ksh[i] = sg.K[i];
    __syncthreads();
    int j = tid & 63, slot = tid >> 6;
    int n = lb * 4 + slot;
    if (n >= sg.N) return;
    const float* Er = sg.E + (size_t)n * 64;
    float acc = 0.f;
#pragma unroll
    for (int kk = 0; kk < 64; ++kk) acc += Er[kk] * Ksh[kk * 64 + j];
    int h = j >> 4, dh = j & 15;
    sg.Kout[((size_t)h * sg.N + n) * 16 + dh] = acc;
}

// ===========================================================================
// A^T B partials for all 3 graphs in one dispatch. No atomics (round-2
// lesson: contended float atomics serialize the L2 RMW pipe).
// ===========================================================================
__global__ __launch_bounds__(256) void atb3(const float* __restrict__ c0, const float* __restrict__ c1, const float* __restrict__ c2,
                                            const float* __restrict__ K0, const float* __restrict__ K1, const float* __restrict__ K2,
                                            int N0, int N1, int N2,
                                            float* __restrict__ part) {
    int kidx = blockIdx.x / ATB_B;
    int lb = blockIdx.x % ATB_B;
    const float* cur = (kidx == 0) ? c0 : (kidx == 1 ? c1 : c2);
    const float* Key = (kidx == 0) ? K0 : (kidx == 1 ? K1 : K2);
    int N = (kidx == 0) ? N0 : (kidx == 1 ? N1 : N2);
    int chunk = (N + ATB_B - 1) / ATB_B;
    int tid = threadIdx.x;
    int k = tid & 63, h = tid >> 6;
    const float* Kh = Key + (size_t)h * N * 16;
    float acc[16];
#pragma unroll
    for (int i = 0; i < 16; ++i) acc[i] = 0.f;
    int s = lb * chunk;
    int e = s + chunk;
    if (e > N) e = N;
#pragma unroll 2
    for (int n = s; n < e; ++n) {
        float c = cur[(size_t)n * 64 + k];
        const float4* kr = (const float4*)(Kh + (size_t)n * 16);
        float4 k0 = kr[0], k1 = kr[1], k2 = kr[2], k3 = kr[3];
        acc[0]  += c * k0.x;  acc[1]  += c * k0.y;  acc[2]  += c * k0.z;  acc[3]  += c * k0.w;
        acc[4]  += c * k1.x;  acc[5]  += c * k1.y;  acc[6]  += c * k1.z;  acc[7]  += c * k1.w;
        acc[8]  += c * k2.x;  acc[9]  += c * k2.y;  acc[10] += c * k2.z;  acc[11] += c * k2.w;
        acc[12] += c * k3.x;  acc[13] += c * k3.y;  acc[14] += c * k3.z;  acc[15] += c * k3.w;
    }
    float4* po = (float4*)(part + ((size_t)kidx * ATB_B + lb) * 4096 + k * 64 + h * 16);
    po[0] = make_float4(acc[0],  acc[1],  acc[2],  acc[3]);
    po[1] = make_float4(acc[4],  acc[5],  acc[6],  acc[7]);
    po[2] = make_float4(acc[8],  acc[9],  acc[10], acc[11]);
    po[3] = make_float4(acc[12], acc[13], acc[14], acc[15]);
}

// Mall[k][i] = sum_b part[k][b][i]  — grid 3*16 blocks
__global__ __launch_bounds__(256) void reduce3(const float* __restrict__ part,
                                               float* __restrict__ Mall) {
    int k = blockIdx.x >> 4;
    int i = (blockIdx.x & 15) * 256 + threadIdx.x;
    const float* p = part + (size_t)k * ATB_B * 4096 + i;
    float s = 0.f;
#pragma unroll 8
    for (int b = 0; b < ATB_B; ++b) s += p[(size_t)b * 4096];
    Mall[k * 4096 + i] = s;
}

// ===========================================================================
// Entire small chain VK->t1->ff->ff->pre0->pre2 in ONE kernel.
// One 1024-thread workgroup per graph; ALL stage operands LDS-staged with
// coalesced global loads (round-4 lesson: per-thread W-row reads = 64
// cache lines/instr serialized through one CU's TA -> 254us).
// W chunks stored transposed with stride 129 (2-way bank alias = free).
// ===========================================================================
__global__ __launch_bounds__(1024) void chain3(const float* __restrict__ Mall,
                                               const float* __restrict__ pV,
                                               const float* __restrict__ hyp3,
                                               const float* __restrict__ W1,
                                               const float* __restrict__ W2,
                                               const float* __restrict__ Vt,
                                               float* __restrict__ pre2all, int l) {
    int kg = blockIdx.x;
    const float* M    = Mall + kg * 4096;
    const float* pVk  = pV + kg * 4096;
    const float* hyp  = hyp3 + kg * 8192;
    const float* W1kl = W1 + (size_t)(kg * 2 + l) * 16384;
    const float* W2kl = W2 + (size_t)(kg * 2 + l) * 16384;
    const float* Vk   = Vt + kg * 4096;
    float* pre2 = pre2all + kg * 1024;

    __shared__ float tA[8192];
    __shared__ float tB[8192];
    __shared__ float hypsh[8192];
    __shared__ float shW[64 * 129 + 64];   // reused: M+pV -> W chunks -> V
    __shared__ float VKs[1024];

    int tid = threadIdx.x;
    // stage hyp, M, pV (all coalesced)
    for (int i = tid; i < 8192; i += 1024) hypsh[i] = hyp[i];
    for (int i = tid; i < 4096; i += 1024) { shW[i] = M[i]; shW[4096 + i] = pVk[i]; }
    __syncthreads();

    // VK[h,d1,d2] = sum_k pV[k,h*16+d1] * M[k,h*16+d2]
    {
        int d2 = tid & 15, d1 = (tid >> 4) & 15, h = tid >> 8;
        float s = 0.f;
#pragma unroll
        for (int k2 = 0; k2 < 64; ++k2)
            s += shW[4096 + k2 * 64 + h * 16 + d1] * shW[k2 * 64 + h * 16 + d2];
        VKs[tid] = s;
    }
    __syncthreads();

    // t1[d,m] = sum_d2 VK[d*16+d2]*hyp[(h*16+d2)*128+m]   -> tA
    for (int i = tid; i < 8192; i += 1024) {
        int m = i & 127, d = i >> 7, h = d >> 4;
        float s = 0.f;
#pragma unroll
        for (int d2 = 0; d2 < 16; ++d2) s += VKs[d * 16 + d2] * hypsh[(h * 16 + d2) * 128 + m];
        tA[i] = s;
    }
    __syncthreads();

    // ff1: tB = leaky(tA @ W1^T) + tA    (W1 staged per 64-col chunk)
    {
        float acc[8];
#pragma unroll
        for (int j = 0; j < 8; ++j) acc[j] = 0.f;
        for (int c = 0; c < 2; ++c) {
            __syncthreads();
            for (int t = tid; t < 8192; t += 1024) {
                int m = t >> 6, mml = t & 63;
                shW[mml * 129 + m] = W1kl[m * 128 + c * 64 + mml];
            }
            __syncthreads();
#pragma unroll
            for (int j = 0; j < 8; ++j) {
                int i = tid + j * 1024;
                int m = i & 127, d = i >> 7;
                const float* tr = tA + d * 128 + c * 64;
                float s = 0.f;
#pragma unroll
                for (int mm = 0; mm < 64; ++mm) s += tr[mm] * shW[mm * 129 + m];
                acc[j] += s;
            }
        }
#pragma unroll
        for (int j = 0; j < 8; ++j) {
            int i = tid + j * 1024;
            float s = acc[j];
            tB[i] = (s >= 0.f ? s : 0.5f * s) + tA[i];
        }
    }
    __syncthreads();

    // ff2: tA = leaky(tB @ W2^T) + tB
    {
        float acc[8];
#pragma unroll
        for (int j = 0; j < 8; ++j) acc[j] = 0.f;
        for (int c = 0; c < 2; ++c) {
            __syncthreads();
            for (int t = tid; t < 8192; t += 1024) {
                int m = t >> 6, mml = t & 63;
                shW[mml * 129 + m] = W2kl[m * 128 + c * 64 + mml];
            }
            __syncthreads();
#pragma unroll
            for (int j = 0; j < 8; ++j) {
                int i = tid + j * 1024;
                int m = i & 127, d = i >> 7;
                const float* tr = tB + d * 128 + c * 64;
                float s = 0.f;
#pragma unroll
                for (int mm = 0; mm < 64; ++mm) s += tr[mm] * shW[mm * 129 + m];
                acc[j] += s;
            }
        }
#pragma unroll
        for (int j = 0; j < 8; ++j) {
            int i = tid + j * 1024;
            float s = acc[j];
            tA[i] = (s >= 0.f ? s : 0.5f * s) + tB[i];
        }
    }
    __syncthreads();

    // stage V into shW[0:4096] (coalesced)
    for (int i = tid; i < 4096; i += 1024) shW[i] = Vk[i];
    __syncthreads();

    // pre0[m,dd] = sum_d t3[d,m]*V[d,dd]   -> tB
    for (int i = tid; i < 8192; i += 1024) {
        int dd = i & 63, m = i >> 6;
        float s = 0.f;
#pragma unroll
        for (int d = 0; d < 64; ++d) s += tA[d * 128 + m] * shW[d * 64 + dd];
        tB[i] = s;
    }
    __syncthreads();

    // pre2[h,d1,d2] = sum_m hyp[h,d1,m]*pre0[m,h*16+d2]
    {
        int d2 = tid & 15, d1 = (tid >> 4) & 15, h = tid >> 8;
        float s = 0.f;
#pragma unroll
        for (int m = 0; m < 128; ++m)
            s += hypsh[(h * 16 + d1) * 128 + m] * tB[m * 64 + h * 16 + d2];
        pre2[tid] = s;
    }
}

// ===========================================================================
// Expand (Key @ pre2), 3 segments, one dispatch.
// mode 0: out1 = s ; out2 = in + s      (nxt, tot)
// mode 1: out1 = in + s                 (lat)
// ===========================================================================
struct ESeg { const float* Key; const float* pre2; const float* in; float* out1; float* out2; int N; };
struct Exp3Args { ESeg s0, s1, s2; int b1, b2; };

__global__ __launch_bounds__(256) void expand3(Exp3Args A, int mode) {
    int b = blockIdx.x;
    ESeg sg; int lb;
    if (b >= A.b2)      { sg = A.s2; lb = b - A.b2; }
    else if (b >= A.b1) { sg = A.s1; lb = b - A.b1; }
    else                { sg = A.s0; lb = b; }
    __shared__ float p2[1024];
    int tid = threadIdx.x;
    for (int i = tid; i < 1024; i += 256) p2[i] = sg.pre2[i];
    __syncthreads();
    int j = tid & 63, slot = tid >> 6;
    int n = lb * 4 + slot;
    if (n >= sg.N) return;
    int h = j >> 4, d2 = j & 15;
    const float* kr = sg.Key + ((size_t)h * sg.N + n) * 16;
    float s = 0.f;
#pragma unroll
    for (int d1 = 0; d1 < 16; ++d1) s += kr[d1] * p2[(h * 16 + d1) * 16 + d2];
    size_t o = (size_t)n * 64 + j;
    if (mode == 0) { sg.out1[o] = s; sg.out2[o] = sg.in[o] + s; }
    else           { sg.out1[o] = sg.in[o] + s; }
}

// ---------------------------------------------------------------------------
// Build hyp3[k][h,dh,m] = Hyper[k][m, h*16+dh] and copy Hyper -> out
// ---------------------------------------------------------------------------
__global__ __launch_bounds__(256) void hyp_kernel(const float* __restrict__ Hyper,
                                                  float* __restrict__ hyp3,
                                                  float* __restrict__ out,
                                                  size_t off0, size_t off1, size_t off2) {
    int i = blockIdx.x * 256 + threadIdx.x;
    if (i >= 3 * 8192) return;
    int k = i / 8192, r = i % 8192;
    float v = Hyper[i];
    size_t off = (k == 0) ? off0 : ((k == 1) ? off1 : off2);
    out[off + r] = v;
    int m = r >> 6, dcol = r & 63;
    hyp3[k * 8192 + dcol * 128 + m] = v;
}

// ===========================================================================
// FALLBACK kernels (atomic-scatter path, used only if ws too small)
// ===========================================================================
__global__ __launch_bounds__(256) void spmm_k(const int* __restrict__ rows,
                                              const int* __restrict__ cols,
                                              const float* __restrict__ vals,
                                              const float* __restrict__ X,
                                              float* __restrict__ out, int nnz) {
    int gid = blockIdx.x * 256 + threadIdx.x;
    int e = gid >> 6;
    if (e >= nnz) return;
    int d = gid & 63;
    int r = rows[e], c = cols[e];
    float v = vals[e];
    atomicAdd(&out[(size_t)r * 64 + d], v * X[(size_t)c * 64 + d]);
}

__global__ __launch_bounds__(256) void add3_kernel(const float* __restrict__ base,
                                                   const float* __restrict__ a,
                                                   const float* __restrict__ b,
                                                   float* __restrict__ outb, size_t n) {
    size_t i = (size_t)blockIdx.x * 256 + threadIdx.x;
    if (i >= n) return;
    outb[i] = base[i] + a[i] + b[i];
}

__global__ __launch_bounds__(256) void key_gemm(const float* __restrict__ E,
                                                const float* __restrict__ K,
                                                float* __restrict__ Kout, int N) {
    __shared__ float Ksh[4096];
    int tid = threadIdx.x;
    for (int i = tid; i < 4096; i += 256) Ksh[i] = K[i];
    __syncthreads();
    int j = tid & 63, slot = tid >> 6;
    int n = blockIdx.x * 4 + slot;
    if (n >= N) return;
    const float* Er = E + (size_t)n * 64;
    float acc = 0.f;
#pragma unroll
    for (int kk = 0; kk < 64; ++kk) acc += Er[kk] * Ksh[kk * 64 + j];
    int h = j >> 4, dh = j & 15;
    Kout[((size_t)h * N + n) * 16 + dh] = acc;
}

#define ATB_ROWS 128
__global__ __launch_bounds__(256) void atb_k(const float* __restrict__ cur,
                                             const float* __restrict__ Key,
                                             float* __restrict__ M, int N) {
    int tid = threadIdx.x;
    int k = tid & 63, h = tid >> 6;
    const float* Kh = Key + (size_t)h * N * 16;
    float acc[16];
#pragma unroll
    for (int i = 0; i < 16; ++i) acc[i] = 0.f;
    int s = blockIdx.x * ATB_ROWS;
    int e = s + ATB_ROWS;
    if (e > N) e = N;
    for (int n = s; n < e; ++n) {
        float c = cur[(size_t)n * 64 + k];
        const float4* kr = (const float4*)(Kh + (size_t)n * 16);
        float4 k0 = kr[0], k1 = kr[1], k2 = kr[2], k3 = kr[3];
        acc[0]  += c * k0.x;  acc[1]  += c * k0.y;  acc[2]  += c * k0.z;  acc[3]  += c * k0.w;
        acc[4]  += c * k1.x;  acc[5]  += c * k1.y;  acc[6]  += c * k1.z;  acc[7]  += c * k1.w;
        acc[8]  += c * k2.x;  acc[9]  += c * k2.y;  acc[10] += c * k2.z;  acc[11] += c * k2.w;
        acc[12] += c * k3.x;  acc[13] += c * k3.y;  acc[14] += c * k3.z;  acc[15] += c * k3.w;
    }
#pragma unroll
    for (int d2 = 0; d2 < 16; ++d2)
        atomicAdd(&M[k * 64 + h * 16 + d2], acc[d2]);
}

__global__ __launch_bounds__(256) void vk_small(const float* __restrict__ M,
                                                const float* __restrict__ pV,
                                                float* __restrict__ VK) {
    int i = blockIdx.x * 256 + threadIdx.x;
    if (i >= 1024) return;
    int d2 = i & 15, d1 = (i >> 4) & 15, h = i >> 8;
    float s = 0.f;
#pragma unroll
    for (int k = 0; k < 64; ++k)
        s += pV[k * 64 + h * 16 + d1] * M[k * 64 + h * 16 + d2];
    VK[i] = s;
}

__global__ __launch_bounds__(256) void t1_kernel(const float* __restrict__ VK,
                                                 const float* __restrict__ hyp,
                                                 float* __restrict__ t1) {
    int i = blockIdx.x * 256 + threadIdx.x;
    if (i >= 8192) return;
    int m = i & 127, d = i >> 7, h = d >> 4;
    float s = 0.f;
#pragma unroll
    for (int d2 = 0; d2 < 16; ++d2) s += VK[d * 16 + d2] * hyp[(h * 16 + d2) * 128 + m];
    t1[i] = s;
}

__global__ __launch_bounds__(256) void ff_kernel(const float* __restrict__ tin,
                                                 const float* __restrict__ W,
                                                 float* __restrict__ tout) {
    int i = blockIdx.x * 256 + threadIdx.x;
    if (i >= 8192) return;
    int m = i & 127, d = i >> 7;
    const float* tr = tin + d * 128;
    const float* wr = W + m * 128;
    float s = 0.f;
#pragma unroll
    for (int mm = 0; mm < 128; ++mm) s += tr[mm] * wr[mm];
    tout[i] = (s >= 0.f ? s : 0.5f * s) + tin[i];
}

__global__ __launch_bounds__(256) void pre0_kernel(const float* __restrict__ t3,
                                                   const float* __restrict__ V,
                                                   float* __restrict__ pre0) {
    int i = blockIdx.x * 256 + threadIdx.x;
    if (i >= 8192) return;
    int dd = i & 63, m = i >> 6;
    float s = 0.f;
#pragma unroll
    for (int d = 0; d < 64; ++d) s += t3[d * 128 + m] * V[d * 64 + dd];
    pre0[m * 64 + dd] = s;
}

__global__ __launch_bounds__(256) void pre2_kernel(const float* __restrict__ hyp,
                                                   const float* __restrict__ pre0,
                                                   float* __restrict__ pre2) {
    int i = blockIdx.x * 256 + threadIdx.x;
    if (i >= 1024) return;
    int d2 = i & 15, d1 = (i >> 4) & 15, h = i >> 8;
    float s = 0.f;
#pragma unroll
    for (int m = 0; m < 128; ++m) s += hyp[(h * 16 + d1) * 128 + m] * pre0[m * 64 + h * 16 + d2];
    pre2[i] = s;
}

__global__ __launch_bounds__(256) void expand0_kernel(const float* __restrict__ Key,
                                                      const float* __restrict__ pre2,
                                                      const float* __restrict__ E0,
                                                      float* __restrict__ nxt,
                                                      float* __restrict__ tot, int N) {
    __shared__ float p2[1024];
    int tid = threadIdx.x;
    for (int i = tid; i < 1024; i += 256) p2[i] = pre2[i];
    __syncthreads();
    int j = tid & 63, slot = tid >> 6;
    int n = blockIdx.x * 4 + slot;
    if (n >= N) return;
    int h = j >> 4, d2 = j & 15;
    const float* kr = Key + ((size_t)h * N + n) * 16;
    float s = 0.f;
#pragma unroll
    for (int d1 = 0; d1 < 16; ++d1) s += kr[d1] * p2[(h * 16 + d1) * 16 + d2];
    size_t o = (size_t)n * 64 + j;
    nxt[o] = s;
    tot[o] = E0[o] + s;
}

__global__ __launch_bounds__(256) void expand1_kernel(const float* __restrict__ Key,
                                                      const float* __restrict__ pre2,
                                                      const float* __restrict__ tot,
                                                      float* __restrict__ outb, int N) {
    __shared__ float p2[1024];
    int tid = threadIdx.x;
    for (int i = tid; i < 1024; i += 256) p2[i] = pre2[i];
    __syncthreads();
    int j = tid & 63, slot = tid >> 6;
    int n = blockIdx.x * 4 + slot;
    if (n >= N) return;
    int h = j >> 4, d2 = j & 15;
    const float* kr = Key + ((size_t)h * N + n) * 16;
    float s = 0.f;
#pragma unroll
    for (int d1 = 0; d1 < 16; ++d1) s += kr[d1] * p2[(h * 16 + d1) * 16 + d2];
    size_t o = (size_t)n * 64 + j;
    outb[o] = tot[o] + s;
}

// ===========================================================================
extern "C" void kernel_launch(void* const* d_in, const int* in_sizes, int n_in,
                              void* d_out, int out_size, void* d_ws, size_t ws_size,
                              hipStream_t stream) {
    const float* uE      = (const float*)d_in[0];
    const float* iE      = (const float*)d_in[1];
    const float* Ks      = (const float*)d_in[2];
    const float* Hyper   = (const float*)d_in[3];
    const float* Vt      = (const float*)d_in[4];
    const float* pV      = (const float*)d_in[5];
    const float* W1      = (const float*)d_in[6];
    const float* W2      = (const float*)d_in[7];
    const int* adj_rows  = (const int*)d_in[8];
    const int* adj_cols  = (const int*)d_in[9];
    const float* adj_vals= (const float*)d_in[10];
    const int* tp_rows   = (const int*)d_in[11];
    const int* tp_cols   = (const int*)d_in[12];
    const float* tp_vals = (const float*)d_in[13];
    const int* uu_rows   = (const int*)d_in[14];
    const int* uu_cols   = (const int*)d_in[15];
    const float* uu_vals = (const float*)d_in[16];

    const int U = in_sizes[0] / 64;
    const int I = in_sizes[1] / 64;
    const int nnz_ui = in_sizes[8];
    const int nnz_uu = in_sizes[14];
    const size_t UD = (size_t)U * 64, ID = (size_t)I * 64;

    float* out = (float*)d_out;
    const size_t o_uE0 = 0;
    const size_t o_iE0 = UD;
    const size_t o_ulat = UD + ID;
    const size_t o_ilat = 2 * UD + ID;
    const size_t o_uKey = 2 * UD + 2 * ID;
    const size_t o_iKey = 3 * UD + 2 * ID;
    const size_t o_uHyp = 3 * UD + 3 * ID;
    const size_t o_iHyp = o_uHyp + 8192;
    const size_t o_uuE0 = o_iHyp + 8192;
    const size_t o_uulat = o_uuE0 + UD;
    const size_t o_uuKey = o_uulat + UD;
    const size_t o_uuHyp = o_uuKey + UD;

    // ---- new-path ws layout ----
    float* ws   = (float*)d_ws;
    float* B1   = ws;               // UD: h1u -> nxt_u
    float* B2   = B1 + UD;          // ID: h1i -> nxt_i
    float* B3   = B2 + ID;          // UD: tot_u
    float* Ti   = B3 + UD;          // ID: tot_i
    float* Buu1 = Ti + ID;          // UD: h1uu -> nxt_uu
    float* Tuu  = Buu1 + UD;        // UD: tot_uu
    float* hyp3 = Tuu + UD;              // 24576
    float* Mall = hyp3 + 24576;          // 12288
    float* pre2all = Mall + 12288;       // 3072
    int2*  edge_a = (int2*)(pre2all + 3072);
    int2*  edge_t = edge_a + nnz_ui;
    int2*  edge_u = edge_t + nnz_ui;
    int*   rpAll  = (int*)(edge_u + nnz_uu);          // (U+1)+(I+1)+(U+1)
    int*   curAll = rpAll + (U + 1) + (I + 1) + (U + 1);  // counts (hist_w out)
    int*   bsumAll= curAll + U + I + U;               // 3*1024
    float* partw  = (float*)(bsumAll + 3072);         // 3*ATB_B*4096
    size_t need_bytes = (size_t)((char*)(partw + (size_t)3 * ATB_B * 4096) - (char*)d_ws);
    const int nbA = (U + 255) / 256, nbT = (I + 255) / 256, nbU = (U + 255) / 256;
    const bool use_new = (ws_size >= need_bytes) && (nbA <= 1024) && (nbT <= 1024);

    int* rp_a = rpAll;
    int* rp_t = rpAll + (U + 1);
    int* rp_u = rpAll + (U + 1) + (I + 1);

    if (use_new) {
        // ---- windowed CSR build for all 3 graphs (5 dispatches, no memset) ----
        const int wU = (U + WROWS - 1) / WROWS;
        const int wI = (I + WROWS - 1) / WROWS;
        hist_w<<<wU + wI + wU, 256, 0, stream>>>(adj_rows, tp_rows, uu_rows,
                                                 nnz_ui, nnz_uu, curAll, U, I, wU, wI);
        scan_part3<<<nbA + nbT + nbU, 256, 0, stream>>>(curAll, bsumAll, U, I, nbA, nbT);
        scan_top3<<<3, 1024, 0, stream>>>(bsumAll, nbA, nbT, nbU);
        scan_final3<<<nbA + nbT + nbU, 256, 0, stream>>>(curAll, bsumAll, rpAll,
                                                         U, I, nbA, nbT, nnz_ui, nnz_uu);
        scatter_w<<<wU + wI + wU, 256, 0, stream>>>(
            adj_rows, adj_cols, adj_vals, tp_rows, tp_cols, tp_vals,
            uu_rows, uu_cols, uu_vals, rpAll, edge_a, nnz_ui, nnz_uu, U, I, wU, wI);

        // ---- gather SpMM phases (3 dispatches) ----
        // S1: B2 = A^T.uE ; B1 = A.iE
        {
            Spmm3Args A;
            A.s0 = { rp_t, edge_t, uE, nullptr, nullptr, B2, I };
            A.s1 = { rp_a, edge_a, iE, nullptr, nullptr, B1, U };
            A.s2 = { nullptr, nullptr, nullptr, nullptr, nullptr, nullptr, 0 };
            A.n0 = I; A.n01 = I + U; A.total = I + U;
            spmm3<<<(int)(((size_t)A.total * 64 + 255) / 256), 256, 0, stream>>>(A);
        }
        // S2: uE0 = uE+B1+A.B2 ; iE0 = iE+B2+A^T.B1 ; Buu1 = Buu.uE
        {
            Spmm3Args A;
            A.s0 = { rp_a, edge_a, B2, uE, B1, out + o_uE0, U };
            A.s1 = { rp_t, edge_t, B1, iE, B2, out + o_iE0, I };
            A.s2 = { rp_u, edge_u, uE, nullptr, nullptr, Buu1, U };
            A.n0 = U; A.n01 = U + I; A.total = U + I + U;
            spmm3<<<(int)(((size_t)A.total * 64 + 255) / 256), 256, 0, stream>>>(A);
        }
        // S3: uuE0 = uE + Buu1 + Buu.Buu1
        {
            Spmm3Args A;
            A.s0 = { rp_u, edge_u, Buu1, uE, Buu1, out + o_uuE0, U };
            A.s1 = { nullptr, nullptr, nullptr, nullptr, nullptr, nullptr, 0 };
            A.s2 = A.s1;
            A.n0 = U; A.n01 = U; A.total = U;
            spmm3<<<(int)(((size_t)A.total * 64 + 255) / 256), 256, 0, stream>>>(A);
        }

        hyp_kernel<<<(3 * 8192 + 255) / 256, 256, 0, stream>>>(Hyper, hyp3, out,
                                                               o_uHyp, o_iHyp, o_uuHyp);

        // ---- keys for all 3 graphs (1 dispatch) ----
        const int gb0 = (U + 3) / 4, gb1 = (I + 3) / 4, gb2 = (U + 3) / 4;
        {
            Key3Args A;
            A.s0 = { out + o_uE0,  Ks,        out + o_uKey,  U };
            A.s1 = { out + o_iE0,  Ks + 4096, out + o_iKey,  I };
            A.s2 = { out + o_uuE0, Ks + 8192, out + o_uuKey, U };
            A.b1 = gb0; A.b2 = gb0 + gb1;
            key3<<<gb0 + gb1 + gb2, 256, 0, stream>>>(A);
        }

        const float* Key0 = out + o_uKey;
        const float* Key1 = out + o_iKey;
        const float* Key2 = out + o_uuKey;

        for (int l = 0; l < 2; ++l) {
            const float* c0 = (l == 0) ? (out + o_uE0)  : B1;
            const float* c1 = (l == 0) ? (out + o_iE0)  : B2;
            const float* c2 = (l == 0) ? (out + o_uuE0) : Buu1;

            atb3<<<3 * ATB_B, 256, 0, stream>>>(c0, c1, c2, Key0, Key1, Key2, U, I, U, partw);
            reduce3<<<48, 256, 0, stream>>>(partw, Mall);
            chain3<<<3, 1024, 0, stream>>>(Mall, pV, hyp3, W1, W2, Vt, pre2all, l);

            Exp3Args E;
            E.b1 = gb0; E.b2 = gb0 + gb1;
            if (l == 0) {
                E.s0 = { Key0, pre2all,        out + o_uE0,  B1,   B3,  U };
                E.s1 = { Key1, pre2all + 1024, out + o_iE0,  B2,   Ti,  I };
                E.s2 = { Key2, pre2all + 2048, out + o_uuE0, Buu1, Tuu, U };
                expand3<<<gb0 + gb1 + gb2, 256, 0, stream>>>(E, 0);
            } else {
                E.s0 = { Key0, pre2all,        B3,  out + o_ulat,  nullptr, U };
                E.s1 = { Key1, pre2all + 1024, Ti,  out + o_ilat,  nullptr, I };
                E.s2 = { Key2, pre2all + 2048, Tuu, out + o_uulat, nullptr, U };
                expand3<<<gb0 + gb1 + gb2, 256, 0, stream>>>(E, 1);
            }
        }
    } else {
        // ---- fallback: original atomic-scatter path (round-0 structure) ----
        float* fB1 = ws;
        float* fB2 = fB1 + UD;
        float* fB3 = fB2 + ID;
        float* fhyp3 = fB2;
        float* fVK  = fhyp3 + 3 * 8192;
        float* ft1  = fVK + 1024;
        float* ft2  = ft1 + 8192;
        float* ft3  = ft2 + 8192;
        float* fpre0 = ft3 + 8192;
        float* fpre2 = fpre0 + 8192;
        float* fM   = fpre2 + 1024;

        const int g_ui = (int)(((size_t)nnz_ui * 64 + 255) / 256);
        const int g_uu = (int)(((size_t)nnz_uu * 64 + 255) / 256);
        const int gU = (int)((UD + 255) / 256);
        const int gI = (int)((ID + 255) / 256);
        hipMemsetAsync(fB1, 0, UD * sizeof(float), stream);
        spmm_k<<<g_ui, 256, 0, stream>>>(adj_rows, adj_cols, adj_vals, iE, fB1, nnz_ui);
        hipMemsetAsync(fB2, 0, ID * sizeof(float), stream);
        spmm_k<<<g_ui, 256, 0, stream>>>(tp_rows, tp_cols, tp_vals, uE, fB2, nnz_ui);
        hipMemsetAsync(fB3, 0, UD * sizeof(float), stream);
        spmm_k<<<g_ui, 256, 0, stream>>>(adj_rows, adj_cols, adj_vals, fB2, fB3, nnz_ui);
        add3_kernel<<<gU, 256, 0, stream>>>(uE, fB1, fB3, out + o_uE0, UD);
        hipMemsetAsync(fB3, 0, ID * sizeof(float), stream);
        spmm_k<<<g_ui, 256, 0, stream>>>(tp_rows, tp_cols, tp_vals, fB1, fB3, nnz_ui);
        add3_kernel<<<gI, 256, 0, stream>>>(iE, fB2, fB3, out + o_iE0, ID);
        hipMemsetAsync(fB1, 0, UD * sizeof(float), stream);
        spmm_k<<<g_uu, 256, 0, stream>>>(uu_rows, uu_cols, uu_vals, uE, fB1, nnz_uu);
        hipMemsetAsync(fB3, 0, UD * sizeof(float), stream);
        spmm_k<<<g_uu, 256, 0, stream>>>(uu_rows, uu_cols, uu_vals, fB1, fB3, nnz_uu);
        add3_kernel<<<gU, 256, 0, stream>>>(uE, fB1, fB3, out + o_uuE0, UD);

        hyp_kernel<<<(3 * 8192 + 255) / 256, 256, 0, stream>>>(Hyper, fhyp3, out,
                                                               o_uHyp, o_iHyp, o_uuHyp);

        const int    Narr[3] = { U, I, U };
        const size_t oE[3]   = { o_uE0, o_iE0, o_uuE0 };
        const size_t oK[3]   = { o_uKey, o_iKey, o_uuKey };
        const size_t oL[3]   = { o_ulat, o_ilat, o_uulat };

        for (int k = 0; k < 3; ++k) {
            int N = Narr[k];
            const float* E0k = out + oE[k];
            float* Keyk = out + oK[k];
            const float* Ksk = Ks + k * 4096;
            const float* pVk = pV + k * 4096;
            const float* Vk  = Vt + k * 4096;
            const float* hypk = fhyp3 + k * 8192;

            key_gemm<<<(N + 3) / 4, 256, 0, stream>>>(E0k, Ksk, Keyk, N);

            for (int l = 0; l < 2; ++l) {
                const float* W1kl = W1 + (size_t)(k * 2 + l) * 16384;
                const float* W2kl = W2 + (size_t)(k * 2 + l) * 16384;

                hipMemsetAsync(fM, 0, 4096 * sizeof(float), stream);
                atb_k<<<(N + ATB_ROWS - 1) / ATB_ROWS, 256, 0, stream>>>(
                    (l == 0) ? E0k : fB1, Keyk, fM, N);
                vk_small<<<4, 256, 0, stream>>>(fM, pVk, fVK);
                t1_kernel<<<32, 256, 0, stream>>>(fVK, hypk, ft1);
                ff_kernel<<<32, 256, 0, stream>>>(ft1, W1kl, ft2);
                ff_kernel<<<32, 256, 0, stream>>>(ft2, W2kl, ft3);
                pre0_kernel<<<32, 256, 0, stream>>>(ft3, Vk, fpre0);
                pre2_kernel<<<4, 256, 0, stream>>>(hypk, fpre0, fpre2);

                if (l == 0) {
                    expand0_kernel<<<(N + 3) / 4, 256, 0, stream>>>(Keyk, fpre2, E0k, fB1, fB3, N);
                } else {
                    expand1_kernel<<<(N + 3) / 4, 256, 0, stream>>>(Keyk, fpre2, fB3, out + oL[k], N);
                }
            }
        }
    }
}

// Round 8
// 1639.518 us; speedup vs baseline: 3.3674x; 3.3674x over previous
//
#include <hip/hip_runtime.h>

#define ATB_B 256

// ===========================================================================
// Fused 3-graph CSR build (round-6 structure: full-occupancy passes).
// Round-7 lesson: NEVER use a low-block-count pass that re-streams the whole
// edge list per block (33 blocks @ 4 waves = latency-bound, 2536us).
// ===========================================================================
__global__ __launch_bounds__(256) void hist3(const int* __restrict__ rA,
                                             const int* __restrict__ rT,
                                             const int* __restrict__ rU,
                                             int nnzA, int nnzU,
                                             int* __restrict__ cntAll, int U, int I) {
    int i = blockIdx.x * 256 + threadIdx.x;
    int tot = 2 * nnzA + nnzU;
    if (i >= tot) return;
    if (i < nnzA) atomicAdd(&cntAll[rA[i]], 1);
    else if (i < 2 * nnzA) atomicAdd(&cntAll[U + rT[i - nnzA]], 1);
    else atomicAdd(&cntAll[U + I + rU[i - 2 * nnzA]], 1);
}

// per-256-chunk sums, 3 segments
__global__ __launch_bounds__(256) void scan_part3(const int* __restrict__ cntAll,
                                                  int* __restrict__ bsumAll,
                                                  int U, int I, int nbA, int nbT) {
    int b = blockIdx.x;
    int lb, n, coff, bsoff;
    if (b < nbA)            { lb = b;             n = U; coff = 0;     bsoff = 0; }
    else if (b < nbA + nbT) { lb = b - nbA;       n = I; coff = U;     bsoff = 1024; }
    else                    { lb = b - nbA - nbT; n = U; coff = U + I; bsoff = 2048; }
    __shared__ int sh[256];
    int tid = threadIdx.x;
    int i = lb * 256 + tid;
    sh[tid] = (i < n) ? cntAll[coff + i] : 0;
    __syncthreads();
    for (int st = 128; st > 0; st >>= 1) {
        if (tid < st) sh[tid] += sh[tid + st];
        __syncthreads();
    }
    if (tid == 0) bsumAll[bsoff + lb] = sh[0];
}

// exclusive scan of block sums: 3 blocks, one per graph
__global__ __launch_bounds__(1024) void scan_top3(int* __restrict__ bsumAll,
                                                  int nbA, int nbT, int nbU) {
    int g = blockIdx.x;
    int nb = (g == 0) ? nbA : (g == 1 ? nbT : nbU);
    int* b = bsumAll + g * 1024;
    __shared__ int sh[1024];
    int tid = threadIdx.x;
    int orig = (tid < nb) ? b[tid] : 0;
    sh[tid] = orig;
    __syncthreads();
    for (int st = 1; st < 1024; st <<= 1) {
        int v = (tid >= st) ? sh[tid - st] : 0;
        __syncthreads();
        sh[tid] += v;
        __syncthreads();
    }
    if (tid < nb) b[tid] = sh[tid] - orig;
}

// in-block exclusive scan + block offset -> rp AND cursor seed (in-place)
__global__ __launch_bounds__(256) void scan_final3(int* __restrict__ curAll,
                                                   const int* __restrict__ bsumAll,
                                                   int* __restrict__ rpAll,
                                                   int U, int I, int nbA, int nbT,
                                                   int nnzA, int nnzU) {
    int b = blockIdx.x;
    int lb, n, coff, bsoff, rpoff, nnz;
    if (b < nbA)            { lb = b;             n = U; coff = 0;     bsoff = 0;    rpoff = 0;                 nnz = nnzA; }
    else if (b < nbA + nbT) { lb = b - nbA;       n = I; coff = U;     bsoff = 1024; rpoff = U + 1;             nnz = nnzA; }
    else                    { lb = b - nbA - nbT; n = U; coff = U + I; bsoff = 2048; rpoff = (U + 1) + (I + 1); nnz = nnzU; }
    __shared__ int sh[256];
    int tid = threadIdx.x;
    int i = lb * 256 + tid;
    int orig = (i < n) ? curAll[coff + i] : 0;
    sh[tid] = orig;
    __syncthreads();
    for (int st = 1; st < 256; st <<= 1) {
        int v = (tid >= st) ? sh[tid - st] : 0;
        __syncthreads();
        sh[tid] += v;
        __syncthreads();
    }
    int ex = sh[tid] - orig + bsumAll[bsoff + lb];
    if (i < n) { rpAll[rpoff + i] = ex; curAll[coff + i] = ex; }
    if (i == n - 1) rpAll[rpoff + n] = nnz;
}

// Row-range-filtered scatter (full grid, coalesced streaming reads).
// Destination region per pass ~4MB -> L2-resident -> dirty lines accumulate
// ~8 edges before writeback (round-6's 192MB line-thrash -> ~payload).
__global__ __launch_bounds__(256) void scatter_r(const int* __restrict__ rows,
                                                 const int* __restrict__ cols,
                                                 const float* __restrict__ vals,
                                                 int* __restrict__ cur,
                                                 int2* __restrict__ edge,
                                                 int nnz, int w0, int wend) {
    int i = blockIdx.x * 256 + threadIdx.x;
    if (i >= nnz) return;
    int r = rows[i];
    if (r < w0 || r >= wend) return;
    int p = atomicAdd(&cur[r], 1);
    edge[p] = make_int2(cols[i], __float_as_int(vals[i]));
}

// ===========================================================================
// Multi-segment gather SpMM: one wave per output row, lane = column d.
// out = gather(row) [+ a0] [+ a1]
// ===========================================================================
struct Seg { const int* rp; const int2* eg; const float* X; const float* a0; const float* a1; float* out; int N; };
struct Spmm3Args { Seg s0, s1, s2; int n0, n01, total; };

__global__ __launch_bounds__(256) void spmm3(Spmm3Args A) {
    int gid = blockIdx.x * 256 + threadIdx.x;
    int r = gid >> 6;
    if (r >= A.total) return;
    int d = gid & 63;
    Seg sg; int lr;
    if (r < A.n0)       { sg = A.s0; lr = r; }
    else if (r < A.n01) { sg = A.s1; lr = r - A.n0; }
    else                { sg = A.s2; lr = r - A.n01; }
    int s = sg.rp[lr], e = sg.rp[lr + 1];
    const float* __restrict__ X = sg.X;
    float acc = 0.f;
    int i = s;
    for (; i + 4 <= e; i += 4) {
        int2 e0 = sg.eg[i], e1 = sg.eg[i + 1], e2 = sg.eg[i + 2], e3 = sg.eg[i + 3];
        float x0 = X[(size_t)e0.x * 64 + d];
        float x1 = X[(size_t)e1.x * 64 + d];
        float x2 = X[(size_t)e2.x * 64 + d];
        float x3 = X[(size_t)e3.x * 64 + d];
        acc += __int_as_float(e0.y) * x0;
        acc += __int_as_float(e1.y) * x1;
        acc += __int_as_float(e2.y) * x2;
        acc += __int_as_float(e3.y) * x3;
    }
    for (; i < e; ++i) {
        int2 ee = sg.eg[i];
        acc += __int_as_float(ee.y) * X[(size_t)ee.x * 64 + d];
    }
    size_t o = (size_t)lr * 64 + d;
    if (sg.a0) acc += sg.a0[o];
    if (sg.a1) acc += sg.a1[o];
    sg.out[o] = acc;
}

// ===========================================================================
// Key = E @ K in (H,N,DH) layout, 3 segments (one dispatch for all graphs)
// ===========================================================================
struct KSeg { const float* E; const float* K; float* Kout; int N; };
struct Key3Args { KSeg s0, s1, s2; int b1, b2; };

__global__ __launch_bounds__(256) void key3(Key3Args A) {
    int b = blockIdx.x;
    KSeg sg; int lb;
    if (b >= A.b2)      { sg = A.s2; lb = b - A.b2; }
    else if (b >= A.b1) { sg = A.s1; lb = b - A.b1; }
    else                { sg = A.s0; lb = b; }
    __shared__ float Ksh[4096];
    int tid = threadIdx.x;
    for (int i = tid; i < 4096; i += 256) Ksh[i] = sg.K[i];
    __syncthreads();
    int j = tid & 63, slot = tid >> 6;
    int n = lb * 4 + slot;
    if (n >= sg.N) return;
    const float* Er = sg.E + (size_t)n * 64;
    float acc = 0.f;
#pragma unroll
    for (int kk = 0; kk < 64; ++kk) acc += Er[kk] * Ksh[kk * 64 + j];
    int h = j >> 4, dh = j & 15;
    sg.Kout[((size_t)h * sg.N + n) * 16 + dh] = acc;
}

// ===========================================================================
// A^T B partials for all 3 graphs in one dispatch. No atomics (round-2
// lesson: contended float atomics serialize the L2 RMW pipe).
// ===========================================================================
__global__ __launch_bounds__(256) void atb3(const float* __restrict__ c0, const float* __restrict__ c1, const float* __restrict__ c2,
                                            const float* __restrict__ K0, const float* __restrict__ K1, const float* __restrict__ K2,
                                            int N0, int N1, int N2,
                                            float* __restrict__ part) {
    int kidx = blockIdx.x / ATB_B;
    int lb = blockIdx.x % ATB_B;
    const float* cur = (kidx == 0) ? c0 : (kidx == 1 ? c1 : c2);
    const float* Key = (kidx == 0) ? K0 : (kidx == 1 ? K1 : K2);
    int N = (kidx == 0) ? N0 : (kidx == 1 ? N1 : N2);
    int chunk = (N + ATB_B - 1) / ATB_B;
    int tid = threadIdx.x;
    int k = tid & 63, h = tid >> 6;
    const float* Kh = Key + (size_t)h * N * 16;
    float acc[16];
#pragma unroll
    for (int i = 0; i < 16; ++i) acc[i] = 0.f;
    int s = lb * chunk;
    int e = s + chunk;
    if (e > N) e = N;
#pragma unroll 2
    for (int n = s; n < e; ++n) {
        float c = cur[(size_t)n * 64 + k];
        const float4* kr = (const float4*)(Kh + (size_t)n * 16);
        float4 k0 = kr[0], k1 = kr[1], k2 = kr[2], k3 = kr[3];
        acc[0]  += c * k0.x;  acc[1]  += c * k0.y;  acc[2]  += c * k0.z;  acc[3]  += c * k0.w;
        acc[4]  += c * k1.x;  acc[5]  += c * k1.y;  acc[6]  += c * k1.z;  acc[7]  += c * k1.w;
        acc[8]  += c * k2.x;  acc[9]  += c * k2.y;  acc[10] += c * k2.z;  acc[11] += c * k2.w;
        acc[12] += c * k3.x;  acc[13] += c * k3.y;  acc[14] += c * k3.z;  acc[15] += c * k3.w;
    }
    float4* po = (float4*)(part + ((size_t)kidx * ATB_B + lb) * 4096 + k * 64 + h * 16);
    po[0] = make_float4(acc[0],  acc[1],  acc[2],  acc[3]);
    po[1] = make_float4(acc[4],  acc[5],  acc[6],  acc[7]);
    po[2] = make_float4(acc[8],  acc[9],  acc[10], acc[11]);
    po[3] = make_float4(acc[12], acc[13], acc[14], acc[15]);
}

// Mall[k][i] = sum_b part[k][b][i]  — grid 3*16 blocks
__global__ __launch_bounds__(256) void reduce3(const float* __restrict__ part,
                                               float* __restrict__ Mall) {
    int k = blockIdx.x >> 4;
    int i = (blockIdx.x & 15) * 256 + threadIdx.x;
    const float* p = part + (size_t)k * ATB_B * 4096 + i;
    float s = 0.f;
#pragma unroll 8
    for (int b = 0; b < ATB_B; ++b) s += p[(size_t)b * 4096];
    Mall[k * 4096 + i] = s;
}

// ===========================================================================
// Entire small chain VK->t1->ff->ff->pre0->pre2 in ONE kernel.
// One 1024-thread workgroup per graph; ALL stage operands LDS-staged with
// coalesced global loads (round-4 lesson). W chunks stored transposed with
// stride 129 (2-way bank alias = free).
// ===========================================================================
__global__ __launch_bounds__(1024) void chain3(const float* __restrict__ Mall,
                                               const float* __restrict__ pV,
                                               const float* __restrict__ hyp3,
                                               const float* __restrict__ W1,
                                               const float* __restrict__ W2,
                                               const float* __restrict__ Vt,
                                               float* __restrict__ pre2all, int l) {
    int kg = blockIdx.x;
    const float* M    = Mall + kg * 4096;
    const float* pVk  = pV + kg * 4096;
    const float* hyp  = hyp3 + kg * 8192;
    const float* W1kl = W1 + (size_t)(kg * 2 + l) * 16384;
    const float* W2kl = W2 + (size_t)(kg * 2 + l) * 16384;
    const float* Vk   = Vt + kg * 4096;
    float* pre2 = pre2all + kg * 1024;

    __shared__ float tA[8192];
    __shared__ float tB[8192];
    __shared__ float hypsh[8192];
    __shared__ float shW[64 * 129 + 64];   // reused: M+pV -> W chunks -> V
    __shared__ float VKs[1024];

    int tid = threadIdx.x;
    for (int i = tid; i < 8192; i += 1024) hypsh[i] = hyp[i];
    for (int i = tid; i < 4096; i += 1024) { shW[i] = M[i]; shW[4096 + i] = pVk[i]; }
    __syncthreads();

    // VK[h,d1,d2] = sum_k pV[k,h*16+d1] * M[k,h*16+d2]
    {
        int d2 = tid & 15, d1 = (tid >> 4) & 15, h = tid >> 8;
        float s = 0.f;
#pragma unroll
        for (int k2 = 0; k2 < 64; ++k2)
            s += shW[4096 + k2 * 64 + h * 16 + d1] * shW[k2 * 64 + h * 16 + d2];
        VKs[tid] = s;
    }
    __syncthreads();

    // t1[d,m] -> tA
    for (int i = tid; i < 8192; i += 1024) {
        int m = i & 127, d = i >> 7, h = d >> 4;
        float s = 0.f;
#pragma unroll
        for (int d2 = 0; d2 < 16; ++d2) s += VKs[d * 16 + d2] * hypsh[(h * 16 + d2) * 128 + m];
        tA[i] = s;
    }
    __syncthreads();

    // ff1: tB = leaky(tA @ W1^T) + tA
    {
        float acc[8];
#pragma unroll
        for (int j = 0; j < 8; ++j) acc[j] = 0.f;
        for (int c = 0; c < 2; ++c) {
            __syncthreads();
            for (int t = tid; t < 8192; t += 1024) {
                int m = t >> 6, mml = t & 63;
                shW[mml * 129 + m] = W1kl[m * 128 + c * 64 + mml];
            }
            __syncthreads();
#pragma unroll
            for (int j = 0; j < 8; ++j) {
                int i = tid + j * 1024;
                int m = i & 127, d = i >> 7;
                const float* tr = tA + d * 128 + c * 64;
                float s = 0.f;
#pragma unroll
                for (int mm = 0; mm < 64; ++mm) s += tr[mm] * shW[mm * 129 + m];
                acc[j] += s;
            }
        }
#pragma unroll
        for (int j = 0; j < 8; ++j) {
            int i = tid + j * 1024;
            float s = acc[j];
            tB[i] = (s >= 0.f ? s : 0.5f * s) + tA[i];
        }
    }
    __syncthreads();

    // ff2: tA = leaky(tB @ W2^T) + tB
    {
        float acc[8];
#pragma unroll
        for (int j = 0; j < 8; ++j) acc[j] = 0.f;
        for (int c = 0; c < 2; ++c) {
            __syncthreads();
            for (int t = tid; t < 8192; t += 1024) {
                int m = t >> 6, mml = t & 63;
                shW[mml * 129 + m] = W2kl[m * 128 + c * 64 + mml];
            }
            __syncthreads();
#pragma unroll
            for (int j = 0; j < 8; ++j) {
                int i = tid + j * 1024;
                int m = i & 127, d = i >> 7;
                const float* tr = tB + d * 128 + c * 64;
                float s = 0.f;
#pragma unroll
                for (int mm = 0; mm < 64; ++mm) s += tr[mm] * shW[mm * 129 + m];
                acc[j] += s;
            }
        }
#pragma unroll
        for (int j = 0; j < 8; ++j) {
            int i = tid + j * 1024;
            float s = acc[j];
            tA[i] = (s >= 0.f ? s : 0.5f * s) + tB[i];
        }
    }
    __syncthreads();

    for (int i = tid; i < 4096; i += 1024) shW[i] = Vk[i];
    __syncthreads();

    // pre0[m,dd] -> tB
    for (int i = tid; i < 8192; i += 1024) {
        int dd = i & 63, m = i >> 6;
        float s = 0.f;
#pragma unroll
        for (int d = 0; d < 64; ++d) s += tA[d * 128 + m] * shW[d * 64 + dd];
        tB[i] = s;
    }
    __syncthreads();

    // pre2[h,d1,d2]
    {
        int d2 = tid & 15, d1 = (tid >> 4) & 15, h = tid >> 8;
        float s = 0.f;
#pragma unroll
        for (int m = 0; m < 128; ++m)
            s += hypsh[(h * 16 + d1) * 128 + m] * tB[m * 64 + h * 16 + d2];
        pre2[tid] = s;
    }
}

// ===========================================================================
// Expand (Key @ pre2), 3 segments, one dispatch.
// ===========================================================================
struct ESeg { const float* Key; const float* pre2; const float* in; float* out1; float* out2; int N; };
struct Exp3Args { ESeg s0, s1, s2; int b1, b2; };

__global__ __launch_bounds__(256) void expand3(Exp3Args A, int mode) {
    int b = blockIdx.x;
    ESeg sg; int lb;
    if (b >= A.b2)      { sg = A.s2; lb = b - A.b2; }
    else if (b >= A.b1) { sg = A.s1; lb = b - A.b1; }
    else                { sg = A.s0; lb = b; }
    __shared__ float p2[1024];
    int tid = threadIdx.x;
    for (int i = tid; i < 1024; i += 256) p2[i] = sg.pre2[i];
    __syncthreads();
    int j = tid & 63, slot = tid >> 6;
    int n = lb * 4 + slot;
    if (n >= sg.N) return;
    int h = j >> 4, d2 = j & 15;
    const float* kr = sg.Key + ((size_t)h * sg.N + n) * 16;
    float s = 0.f;
#pragma unroll
    for (int d1 = 0; d1 < 16; ++d1) s += kr[d1] * p2[(h * 16 + d1) * 16 + d2];
    size_t o = (size_t)n * 64 + j;
    if (mode == 0) { sg.out1[o] = s; sg.out2[o] = sg.in[o] + s; }
    else           { sg.out1[o] = sg.in[o] + s; }
}

// ---------------------------------------------------------------------------
// Build hyp3[k][h,dh,m] = Hyper[k][m, h*16+dh] and copy Hyper -> out
// ---------------------------------------------------------------------------
__global__ __launch_bounds__(256) void hyp_kernel(const float* __restrict__ Hyper,
                                                  float* __restrict__ hyp3,
                                                  float* __restrict__ out,
                                                  size_t off0, size_t off1, size_t off2) {
    int i = blockIdx.x * 256 + threadIdx.x;
    if (i >= 3 * 8192) return;
    int k = i / 8192, r = i % 8192;
    float v = Hyper[i];
    size_t off = (k == 0) ? off0 : ((k == 1) ? off1 : off2);
    out[off + r] = v;
    int m = r >> 6, dcol = r & 63;
    hyp3[k * 8192 + dcol * 128 + m] = v;
}

// ===========================================================================
// FALLBACK kernels (atomic-scatter path, used only if ws too small)
// ===========================================================================
__global__ __launch_bounds__(256) void spmm_k(const int* __restrict__ rows,
                                              const int* __restrict__ cols,
                                              const float* __restrict__ vals,
                                              const float* __restrict__ X,
                                              float* __restrict__ out, int nnz) {
    int gid = blockIdx.x * 256 + threadIdx.x;
    int e = gid >> 6;
    if (e >= nnz) return;
    int d = gid & 63;
    int r = rows[e], c = cols[e];
    float v = vals[e];
    atomicAdd(&out[(size_t)r * 64 + d], v * X[(size_t)c * 64 + d]);
}

__global__ __launch_bounds__(256) void add3_kernel(const float* __restrict__ base,
                                                   const float* __restrict__ a,
                                                   const float* __restrict__ b,
                                                   float* __restrict__ outb, size_t n) {
    size_t i = (size_t)blockIdx.x * 256 + threadIdx.x;
    if (i >= n) return;
    outb[i] = base[i] + a[i] + b[i];
}

__global__ __launch_bounds__(256) void key_gemm(const float* __restrict__ E,
                                                const float* __restrict__ K,
                                                float* __restrict__ Kout, int N) {
    __shared__ float Ksh[4096];
    int tid = threadIdx.x;
    for (int i = tid; i < 4096; i += 256) Ksh[i] = K[i];
    __syncthreads();
    int j = tid & 63, slot = tid >> 6;
    int n = blockIdx.x * 4 + slot;
    if (n >= N) return;
    const float* Er = E + (size_t)n * 64;
    float acc = 0.f;
#pragma unroll
    for (int kk = 0; kk < 64; ++kk) acc += Er[kk] * Ksh[kk * 64 + j];
    int h = j >> 4, dh = j & 15;
    Kout[((size_t)h * N + n) * 16 + dh] = acc;
}

#define ATB_ROWS 128
__global__ __launch_bounds__(256) void atb_k(const float* __restrict__ cur,
                                             const float* __restrict__ Key,
                                             float* __restrict__ M, int N) {
    int tid = threadIdx.x;
    int k = tid & 63, h = tid >> 6;
    const float* Kh = Key + (size_t)h * N * 16;
    float acc[16];
#pragma unroll
    for (int i = 0; i < 16; ++i) acc[i] = 0.f;
    int s = blockIdx.x * ATB_ROWS;
    int e = s + ATB_ROWS;
    if (e > N) e = N;
    for (int n = s; n < e; ++n) {
        float c = cur[(size_t)n * 64 + k];
        const float4* kr = (const float4*)(Kh + (size_t)n * 16);
        float4 k0 = kr[0], k1 = kr[1], k2 = kr[2], k3 = kr[3];
        acc[0]  += c * k0.x;  acc[1]  += c * k0.y;  acc[2]  += c * k0.z;  acc[3]  += c * k0.w;
        acc[4]  += c * k1.x;  acc[5]  += c * k1.y;  acc[6]  += c * k1.z;  acc[7]  += c * k1.w;
        acc[8]  += c * k2.x;  acc[9]  += c * k2.y;  acc[10] += c * k2.z;  acc[11] += c * k2.w;
        acc[12] += c * k3.x;  acc[13] += c * k3.y;  acc[14] += c * k3.z;  acc[15] += c * k3.w;
    }
#pragma unroll
    for (int d2 = 0; d2 < 16; ++d2)
        atomicAdd(&M[k * 64 + h * 16 + d2], acc[d2]);
}

__global__ __launch_bounds__(256) void vk_small(const float* __restrict__ M,
                                                const float* __restrict__ pV,
                                                float* __restrict__ VK) {
    int i = blockIdx.x * 256 + threadIdx.x;
    if (i >= 1024) return;
    int d2 = i & 15, d1 = (i >> 4) & 15, h = i >> 8;
    float s = 0.f;
#pragma unroll
    for (int k = 0; k < 64; ++k)
        s += pV[k * 64 + h * 16 + d1] * M[k * 64 + h * 16 + d2];
    VK[i] = s;
}

__global__ __launch_bounds__(256) void t1_kernel(const float* __restrict__ VK,
                                                 const float* __restrict__ hyp,
                                                 float* __restrict__ t1) {
    int i = blockIdx.x * 256 + threadIdx.x;
    if (i >= 8192) return;
    int m = i & 127, d = i >> 7, h = d >> 4;
    float s = 0.f;
#pragma unroll
    for (int d2 = 0; d2 < 16; ++d2) s += VK[d * 16 + d2] * hyp[(h * 16 + d2) * 128 + m];
    t1[i] = s;
}

__global__ __launch_bounds__(256) void ff_kernel(const float* __restrict__ tin,
                                                 const float* __restrict__ W,
                                                 float* __restrict__ tout) {
    int i = blockIdx.x * 256 + threadIdx.x;
    if (i >= 8192) return;
    int m = i & 127, d = i >> 7;
    const float* tr = tin + d * 128;
    const float* wr = W + m * 128;
    float s = 0.f;
#pragma unroll
    for (int mm = 0; mm < 128; ++mm) s += tr[mm] * wr[mm];
    tout[i] = (s >= 0.f ? s : 0.5f * s) + tin[i];
}

__global__ __launch_bounds__(256) void pre0_kernel(const float* __restrict__ t3,
                                                   const float* __restrict__ V,
                                                   float* __restrict__ pre0) {
    int i = blockIdx.x * 256 + threadIdx.x;
    if (i >= 8192) return;
    int dd = i & 63, m = i >> 6;
    float s = 0.f;
#pragma unroll
    for (int d = 0; d < 64; ++d) s += t3[d * 128 + m] * V[d * 64 + dd];
    pre0[m * 64 + dd] = s;
}

__global__ __launch_bounds__(256) void pre2_kernel(const float* __restrict__ hyp,
                                                   const float* __restrict__ pre0,
                                                   float* __restrict__ pre2) {
    int i = blockIdx.x * 256 + threadIdx.x;
    if (i >= 1024) return;
    int d2 = i & 15, d1 = (i >> 4) & 15, h = i >> 8;
    float s = 0.f;
#pragma unroll
    for (int m = 0; m < 128; ++m) s += hyp[(h * 16 + d1) * 128 + m] * pre0[m * 64 + h * 16 + d2];
    pre2[i] = s;
}

__global__ __launch_bounds__(256) void expand0_kernel(const float* __restrict__ Key,
                                                      const float* __restrict__ pre2,
                                                      const float* __restrict__ E0,
                                                      float* __restrict__ nxt,
                                                      float* __restrict__ tot, int N) {
    __shared__ float p2[1024];
    int tid = threadIdx.x;
    for (int i = tid; i < 1024; i += 256) p2[i] = pre2[i];
    __syncthreads();
    int j = tid & 63, slot = tid >> 6;
    int n = blockIdx.x * 4 + slot;
    if (n >= N) return;
    int h = j >> 4, d2 = j & 15;
    const float* kr = Key + ((size_t)h * N + n) * 16;
    float s = 0.f;
#pragma unroll
    for (int d1 = 0; d1 < 16; ++d1) s += kr[d1] * p2[(h * 16 + d1) * 16 + d2];
    size_t o = (size_t)n * 64 + j;
    nxt[o] = s;
    tot[o] = E0[o] + s;
}

__global__ __launch_bounds__(256) void expand1_kernel(const float* __restrict__ Key,
                                                      const float* __restrict__ pre2,
                                                      const float* __restrict__ tot,
                                                      float* __restrict__ outb, int N) {
    __shared__ float p2[1024];
    int tid = threadIdx.x;
    for (int i = tid; i < 1024; i += 256) p2[i] = pre2[i];
    __syncthreads();
    int j = tid & 63, slot = tid >> 6;
    int n = blockIdx.x * 4 + slot;
    if (n >= N) return;
    int h = j >> 4, d2 = j & 15;
    const float* kr = Key + ((size_t)h * N + n) * 16;
    float s = 0.f;
#pragma unroll
    for (int d1 = 0; d1 < 16; ++d1) s += kr[d1] * p2[(h * 16 + d1) * 16 + d2];
    size_t o = (size_t)n * 64 + j;
    outb[o] = tot[o] + s;
}

// ===========================================================================
extern "C" void kernel_launch(void* const* d_in, const int* in_sizes, int n_in,
                              void* d_out, int out_size, void* d_ws, size_t ws_size,
                              hipStream_t stream) {
    const float* uE      = (const float*)d_in[0];
    const float* iE      = (const float*)d_in[1];
    const float* Ks      = (const float*)d_in[2];
    const float* Hyper   = (const float*)d_in[3];
    const float* Vt      = (const float*)d_in[4];
    const float* pV      = (const float*)d_in[5];
    const float* W1      = (const float*)d_in[6];
    const float* W2      = (const float*)d_in[7];
    const int* adj_rows  = (const int*)d_in[8];
    const int* adj_cols  = (const int*)d_in[9];
    const float* adj_vals= (const float*)d_in[10];
    const int* tp_rows   = (const int*)d_in[11];
    const int* tp_cols   = (const int*)d_in[12];
    const float* tp_vals = (const float*)d_in[13];
    const int* uu_rows   = (const int*)d_in[14];
    const int* uu_cols   = (const int*)d_in[15];
    const float* uu_vals = (const float*)d_in[16];

    const int U = in_sizes[0] / 64;
    const int I = in_sizes[1] / 64;
    const int nnz_ui = in_sizes[8];
    const int nnz_uu = in_sizes[14];
    const size_t UD = (size_t)U * 64, ID = (size_t)I * 64;

    float* out = (float*)d_out;
    const size_t o_uE0 = 0;
    const size_t o_iE0 = UD;
    const size_t o_ulat = UD + ID;
    const size_t o_ilat = 2 * UD + ID;
    const size_t o_uKey = 2 * UD + 2 * ID;
    const size_t o_iKey = 3 * UD + 2 * ID;
    const size_t o_uHyp = 3 * UD + 3 * ID;
    const size_t o_iHyp = o_uHyp + 8192;
    const size_t o_uuE0 = o_iHyp + 8192;
    const size_t o_uulat = o_uuE0 + UD;
    const size_t o_uuKey = o_uulat + UD;
    const size_t o_uuHyp = o_uuKey + UD;

    // ---- new-path ws layout ----
    float* ws   = (float*)d_ws;
    float* B1   = ws;               // UD: h1u -> nxt_u
    float* B2   = B1 + UD;          // ID: h1i -> nxt_i
    float* B3   = B2 + ID;          // UD: tot_u
    float* Ti   = B3 + UD;          // ID: tot_i
    float* Buu1 = Ti + ID;          // UD: h1uu -> nxt_uu
    float* Tuu  = Buu1 + UD;        // UD: tot_uu
    float* hyp3 = Tuu + UD;              // 24576
    float* Mall = hyp3 + 24576;          // 12288
    float* pre2all = Mall + 12288;       // 3072
    int2*  edge_a = (int2*)(pre2all + 3072);
    int2*  edge_t = edge_a + nnz_ui;
    int2*  edge_u = edge_t + nnz_ui;
    int*   rpAll  = (int*)(edge_u + nnz_uu);          // (U+1)+(I+1)+(U+1)
    int*   curAll = rpAll + (U + 1) + (I + 1) + (U + 1);
    int*   bsumAll= curAll + U + I + U;               // 3*1024
    float* partw  = (float*)(bsumAll + 3072);         // 3*ATB_B*4096
    size_t need_bytes = (size_t)((char*)(partw + (size_t)3 * ATB_B * 4096) - (char*)d_ws);
    const int nbA = (U + 255) / 256, nbT = (I + 255) / 256, nbU = (U + 255) / 256;
    const bool use_new = (ws_size >= need_bytes) && (nbA <= 1024) && (nbT <= 1024);

    int* rp_a = rpAll;
    int* rp_t = rpAll + (U + 1);
    int* rp_u = rpAll + (U + 1) + (I + 1);

    if (use_new) {
        // ---- CSR build for all 3 graphs ----
        hipMemsetAsync(curAll, 0, (size_t)(U + I + U) * sizeof(int), stream);
        int totE = 2 * nnz_ui + nnz_uu;
        hist3<<<(totE + 255) / 256, 256, 0, stream>>>(adj_rows, tp_rows, uu_rows,
                                                      nnz_ui, nnz_uu, curAll, U, I);
        scan_part3<<<nbA + nbT + nbU, 256, 0, stream>>>(curAll, bsumAll, U, I, nbA, nbT);
        scan_top3<<<3, 1024, 0, stream>>>(bsumAll, nbA, nbT, nbU);
        scan_final3<<<nbA + nbT + nbU, 256, 0, stream>>>(curAll, bsumAll, rpAll,
                                                         U, I, nbA, nbT, nnz_ui, nnz_uu);
        // Row-range-filtered scatters: dest region ~4MB per pass (L2-resident
        // writes), full-occupancy grids (round-7 lesson).
        const int gSa = (nnz_ui + 255) / 256;
        const int gSu = (nnz_uu + 255) / 256;
        const int hU = (U + 1) / 2, hI = (I + 1) / 2;
        scatter_r<<<gSa, 256, 0, stream>>>(adj_rows, adj_cols, adj_vals, curAll,         edge_a, nnz_ui, 0,  hU);
        scatter_r<<<gSa, 256, 0, stream>>>(adj_rows, adj_cols, adj_vals, curAll,         edge_a, nnz_ui, hU, U);
        scatter_r<<<gSa, 256, 0, stream>>>(tp_rows,  tp_cols,  tp_vals,  curAll + U,     edge_t, nnz_ui, 0,  hI);
        scatter_r<<<gSa, 256, 0, stream>>>(tp_rows,  tp_cols,  tp_vals,  curAll + U,     edge_t, nnz_ui, hI, I);
        scatter_r<<<gSu, 256, 0, stream>>>(uu_rows,  uu_cols,  uu_vals,  curAll + U + I, edge_u, nnz_uu, 0,  hU);
        scatter_r<<<gSu, 256, 0, stream>>>(uu_rows,  uu_cols,  uu_vals,  curAll + U + I, edge_u, nnz_uu, hU, U);

        // ---- gather SpMM phases (3 dispatches) ----
        // S1: B2 = A^T.uE ; B1 = A.iE
        {
            Spmm3Args A;
            A.s0 = { rp_t, edge_t, uE, nullptr, nullptr, B2, I };
            A.s1 = { rp_a, edge_a, iE, nullptr, nullptr, B1, U };
            A.s2 = { nullptr, nullptr, nullptr, nullptr, nullptr, nullptr, 0 };
            A.n0 = I; A.n01 = I + U; A.total = I + U;
            spmm3<<<(int)(((size_t)A.total * 64 + 255) / 256), 256, 0, stream>>>(A);
        }
        // S2: uE0 = uE+B1+A.B2 ; iE0 = iE+B2+A^T.B1 ; Buu1 = Buu.uE
        {
            Spmm3Args A;
            A.s0 = { rp_a, edge_a, B2, uE, B1, out + o_uE0, U };
            A.s1 = { rp_t, edge_t, B1, iE, B2, out + o_iE0, I };
            A.s2 = { rp_u, edge_u, uE, nullptr, nullptr, Buu1, U };
            A.n0 = U; A.n01 = U + I; A.total = U + I + U;
            spmm3<<<(int)(((size_t)A.total * 64 + 255) / 256), 256, 0, stream>>>(A);
        }
        // S3: uuE0 = uE + Buu1 + Buu.Buu1
        {
            Spmm3Args A;
            A.s0 = { rp_u, edge_u, Buu1, uE, Buu1, out + o_uuE0, U };
            A.s1 = { nullptr, nullptr, nullptr, nullptr, nullptr, nullptr, 0 };
            A.s2 = A.s1;
            A.n0 = U; A.n01 = U; A.total = U;
            spmm3<<<(int)(((size_t)A.total * 64 + 255) / 256), 256, 0, stream>>>(A);
        }

        hyp_kernel<<<(3 * 8192 + 255) / 256, 256, 0, stream>>>(Hyper, hyp3, out,
                                                               o_uHyp, o_iHyp, o_uuHyp);

        // ---- keys for all 3 graphs (1 dispatch) ----
        const int gb0 = (U + 3) / 4, gb1 = (I + 3) / 4, gb2 = (U + 3) / 4;
        {
            Key3Args A;
            A.s0 = { out + o_uE0,  Ks,        out + o_uKey,  U };
            A.s1 = { out + o_iE0,  Ks + 4096, out + o_iKey,  I };
            A.s2 = { out + o_uuE0, Ks + 8192, out + o_uuKey, U };
            A.b1 = gb0; A.b2 = gb0 + gb1;
            key3<<<gb0 + gb1 + gb2, 256, 0, stream>>>(A);
        }

        const float* Key0 = out + o_uKey;
        const float* Key1 = out + o_iKey;
        const float* Key2 = out + o_uuKey;

        for (int l = 0; l < 2; ++l) {
            const float* c0 = (l == 0) ? (out + o_uE0)  : B1;
            const float* c1 = (l == 0) ? (out + o_iE0)  : B2;
            const float* c2 = (l == 0) ? (out + o_uuE0) : Buu1;

            atb3<<<3 * ATB_B, 256, 0, stream>>>(c0, c1, c2, Key0, Key1, Key2, U, I, U, partw);
            reduce3<<<48, 256, 0, stream>>>(partw, Mall);
            chain3<<<3, 1024, 0, stream>>>(Mall, pV, hyp3, W1, W2, Vt, pre2all, l);

            Exp3Args E;
            E.b1 = gb0; E.b2 = gb0 + gb1;
            if (l == 0) {
                E.s0 = { Key0, pre2all,        out + o_uE0,  B1,   B3,  U };
                E.s1 = { Key1, pre2all + 1024, out + o_iE0,  B2,   Ti,  I };
                E.s2 = { Key2, pre2all + 2048, out + o_uuE0, Buu1, Tuu, U };
                expand3<<<gb0 + gb1 + gb2, 256, 0, stream>>>(E, 0);
            } else {
                E.s0 = { Key0, pre2all,        B3,  out + o_ulat,  nullptr, U };
                E.s1 = { Key1, pre2all + 1024, Ti,  out + o_ilat,  nullptr, I };
                E.s2 = { Key2, pre2all + 2048, Tuu, out + o_uulat, nullptr, U };
                expand3<<<gb0 + gb1 + gb2, 256, 0, stream>>>(E, 1);
            }
        }
    } else {
        // ---- fallback: original atomic-scatter path (round-0 structure) ----
        float* fB1 = ws;
        float* fB2 = fB1 + UD;
        float* fB3 = fB2 + ID;
        float* fhyp3 = fB2;
        float* fVK  = fhyp3 + 3 * 8192;
        float* ft1  = fVK + 1024;
        float* ft2  = ft1 + 8192;
        float* ft3  = ft2 + 8192;
        float* fpre0 = ft3 + 8192;
        float* fpre2 = fpre0 + 8192;
        float* fM   = fpre2 + 1024;

        const int g_ui = (int)(((size_t)nnz_ui * 64 + 255) / 256);
        const int g_uu = (int)(((size_t)nnz_uu * 64 + 255) / 256);
        const int gU = (int)((UD + 255) / 256);
        const int gI = (int)((ID + 255) / 256);
        hipMemsetAsync(fB1, 0, UD * sizeof(float), stream);
        spmm_k<<<g_ui, 256, 0, stream>>>(adj_rows, adj_cols, adj_vals, iE, fB1, nnz_ui);
        hipMemsetAsync(fB2, 0, ID * sizeof(float), stream);
        spmm_k<<<g_ui, 256, 0, stream>>>(tp_rows, tp_cols, tp_vals, uE, fB2, nnz_ui);
        hipMemsetAsync(fB3, 0, UD * sizeof(float), stream);
        spmm_k<<<g_ui, 256, 0, stream>>>(adj_rows, adj_cols, adj_vals, fB2, fB3, nnz_ui);
        add3_kernel<<<gU, 256, 0, stream>>>(uE, fB1, fB3, out + o_uE0, UD);
        hipMemsetAsync(fB3, 0, ID * sizeof(float), stream);
        spmm_k<<<g_ui, 256, 0, stream>>>(tp_rows, tp_cols, tp_vals, fB1, fB3, nnz_ui);
        add3_kernel<<<gI, 256, 0, stream>>>(iE, fB2, fB3, out + o_iE0, ID);
        hipMemsetAsync(fB1, 0, UD * sizeof(float), stream);
        spmm_k<<<g_uu, 256, 0, stream>>>(uu_rows, uu_cols, uu_vals, uE, fB1, nnz_uu);
        hipMemsetAsync(fB3, 0, UD * sizeof(float), stream);
        spmm_k<<<g_uu, 256, 0, stream>>>(uu_rows, uu_cols, uu_vals, fB1, fB3, nnz_uu);
        add3_kernel<<<gU, 256, 0, stream>>>(uE, fB1, fB3, out + o_uuE0, UD);

        hyp_kernel<<<(3 * 8192 + 255) / 256, 256, 0, stream>>>(Hyper, fhyp3, out,
                                                               o_uHyp, o_iHyp, o_uuHyp);

        const int    Narr[3] = { U, I, U };
        const size_t oE[3]   = { o_uE0, o_iE0, o_uuE0 };
        const size_t oK[3]   = { o_uKey, o_iKey, o_uuKey };
        const size_t oL[3]   = { o_ulat, o_ilat, o_uulat };

        for (int k = 0; k < 3; ++k) {
            int N = Narr[k];
            const float* E0k = out + oE[k];
            float* Keyk = out + oK[k];
            const float* Ksk = Ks + k * 4096;
            const float* pVk = pV + k * 4096;
            const float* Vk  = Vt + k * 4096;
            const float* hypk = fhyp3 + k * 8192;

            key_gemm<<<(N + 3) / 4, 256, 0, stream>>>(E0k, Ksk, Keyk, N);

            for (int l = 0; l < 2; ++l) {
                const float* W1kl = W1 + (size_t)(k * 2 + l) * 16384;
                const float* W2kl = W2 + (size_t)(k * 2 + l) * 16384;

                hipMemsetAsync(fM, 0, 4096 * sizeof(float), stream);
                atb_k<<<(N + ATB_ROWS - 1) / ATB_ROWS, 256, 0, stream>>>(
                    (l == 0) ? E0k : fB1, Keyk, fM, N);
                vk_small<<<4, 256, 0, stream>>>(fM, pVk, fVK);
                t1_kernel<<<32, 256, 0, stream>>>(fVK, hypk, ft1);
                ff_kernel<<<32, 256, 0, stream>>>(ft1, W1kl, ft2);
                ff_kernel<<<32, 256, 0, stream>>>(ft2, W2kl, ft3);
                pre0_kernel<<<32, 256, 0, stream>>>(ft3, Vk, fpre0);
                pre2_kernel<<<4, 256, 0, stream>>>(hypk, fpre0, fpre2);

                if (l == 0) {
                    expand0_kernel<<<(N + 3) / 4, 256, 0, stream>>>(Keyk, fpre2, E0k, fB1, fB3, N);
                } else {
                    expand1_kernel<<<(N + 3) / 4, 256, 0, stream>>>(Keyk, fpre2, fB3, out + oL[k], N);
                }
            }
        }
    }
}

// Round 9
// 1615.106 us; speedup vs baseline: 3.4183x; 1.0151x over previous
//
#include <hip/hip_runtime.h>

#define ATB_B 256

// ===========================================================================
// Fused 3-graph CSR build (round-6 structure: full-occupancy passes).
// Round-7 lesson: NEVER use a low-block-count pass that re-streams the whole
// edge list per block (33 blocks @ 4 waves = latency-bound, 2536us).
// ===========================================================================
__global__ __launch_bounds__(256) void hist3(const int* __restrict__ rA,
                                             const int* __restrict__ rT,
                                             const int* __restrict__ rU,
                                             int nnzA, int nnzU,
                                             int* __restrict__ cntAll, int U, int I) {
    int i = blockIdx.x * 256 + threadIdx.x;
    int tot = 2 * nnzA + nnzU;
    if (i >= tot) return;
    if (i < nnzA) atomicAdd(&cntAll[rA[i]], 1);
    else if (i < 2 * nnzA) atomicAdd(&cntAll[U + rT[i - nnzA]], 1);
    else atomicAdd(&cntAll[U + I + rU[i - 2 * nnzA]], 1);
}

// per-256-chunk sums, 3 segments
__global__ __launch_bounds__(256) void scan_part3(const int* __restrict__ cntAll,
                                                  int* __restrict__ bsumAll,
                                                  int U, int I, int nbA, int nbT) {
    int b = blockIdx.x;
    int lb, n, coff, bsoff;
    if (b < nbA)            { lb = b;             n = U; coff = 0;     bsoff = 0; }
    else if (b < nbA + nbT) { lb = b - nbA;       n = I; coff = U;     bsoff = 1024; }
    else                    { lb = b - nbA - nbT; n = U; coff = U + I; bsoff = 2048; }
    __shared__ int sh[256];
    int tid = threadIdx.x;
    int i = lb * 256 + tid;
    sh[tid] = (i < n) ? cntAll[coff + i] : 0;
    __syncthreads();
    for (int st = 128; st > 0; st >>= 1) {
        if (tid < st) sh[tid] += sh[tid + st];
        __syncthreads();
    }
    if (tid == 0) bsumAll[bsoff + lb] = sh[0];
}

// exclusive scan of block sums: 3 blocks, one per graph
__global__ __launch_bounds__(1024) void scan_top3(int* __restrict__ bsumAll,
                                                  int nbA, int nbT, int nbU) {
    int g = blockIdx.x;
    int nb = (g == 0) ? nbA : (g == 1 ? nbT : nbU);
    int* b = bsumAll + g * 1024;
    __shared__ int sh[1024];
    int tid = threadIdx.x;
    int orig = (tid < nb) ? b[tid] : 0;
    sh[tid] = orig;
    __syncthreads();
    for (int st = 1; st < 1024; st <<= 1) {
        int v = (tid >= st) ? sh[tid - st] : 0;
        __syncthreads();
        sh[tid] += v;
        __syncthreads();
    }
    if (tid < nb) b[tid] = sh[tid] - orig;
}

// in-block exclusive scan + block offset -> rp AND cursor seed (in-place)
__global__ __launch_bounds__(256) void scan_final3(int* __restrict__ curAll,
                                                   const int* __restrict__ bsumAll,
                                                   int* __restrict__ rpAll,
                                                   int U, int I, int nbA, int nbT,
                                                   int nnzA, int nnzU) {
    int b = blockIdx.x;
    int lb, n, coff, bsoff, rpoff, nnz;
    if (b < nbA)            { lb = b;             n = U; coff = 0;     bsoff = 0;    rpoff = 0;                 nnz = nnzA; }
    else if (b < nbA + nbT) { lb = b - nbA;       n = I; coff = U;     bsoff = 1024; rpoff = U + 1;             nnz = nnzA; }
    else                    { lb = b - nbA - nbT; n = U; coff = U + I; bsoff = 2048; rpoff = (U + 1) + (I + 1); nnz = nnzU; }
    __shared__ int sh[256];
    int tid = threadIdx.x;
    int i = lb * 256 + tid;
    int orig = (i < n) ? curAll[coff + i] : 0;
    sh[tid] = orig;
    __syncthreads();
    for (int st = 1; st < 256; st <<= 1) {
        int v = (tid >= st) ? sh[tid - st] : 0;
        __syncthreads();
        sh[tid] += v;
        __syncthreads();
    }
    int ex = sh[tid] - orig + bsumAll[bsoff + lb];
    if (i < n) { rpAll[rpoff + i] = ex; curAll[coff + i] = ex; }
    if (i == n - 1) rpAll[rpoff + n] = nnz;
}

// Row-range-filtered scatter (full grid, coalesced streaming reads).
// Destination region per pass ~4MB -> L2-resident (round-8 win).
__global__ __launch_bounds__(256) void scatter_r(const int* __restrict__ rows,
                                                 const int* __restrict__ cols,
                                                 const float* __restrict__ vals,
                                                 int* __restrict__ cur,
                                                 int2* __restrict__ edge,
                                                 int nnz, int w0, int wend) {
    int i = blockIdx.x * 256 + threadIdx.x;
    if (i >= nnz) return;
    int r = rows[i];
    if (r < w0 || r >= wend) return;
    int p = atomicAdd(&cur[r], 1);
    edge[p] = make_int2(cols[i], __float_as_int(vals[i]));
}

// ===========================================================================
// Multi-segment gather SpMM: one wave per output row, lane = column d.
// out = gather(row) [+ a0] [+ a1]
// ===========================================================================
struct Seg { const int* rp; const int2* eg; const float* X; const float* a0; const float* a1; float* out; int N; };
struct Spmm3Args { Seg s0, s1, s2; int n0, n01, total; };

__global__ __launch_bounds__(256) void spmm3(Spmm3Args A) {
    int gid = blockIdx.x * 256 + threadIdx.x;
    int r = gid >> 6;
    if (r >= A.total) return;
    int d = gid & 63;
    Seg sg; int lr;
    if (r < A.n0)       { sg = A.s0; lr = r; }
    else if (r < A.n01) { sg = A.s1; lr = r - A.n0; }
    else                { sg = A.s2; lr = r - A.n01; }
    int s = sg.rp[lr], e = sg.rp[lr + 1];
    const float* __restrict__ X = sg.X;
    float acc = 0.f;
    int i = s;
    for (; i + 4 <= e; i += 4) {
        int2 e0 = sg.eg[i], e1 = sg.eg[i + 1], e2 = sg.eg[i + 2], e3 = sg.eg[i + 3];
        float x0 = X[(size_t)e0.x * 64 + d];
        float x1 = X[(size_t)e1.x * 64 + d];
        float x2 = X[(size_t)e2.x * 64 + d];
        float x3 = X[(size_t)e3.x * 64 + d];
        acc += __int_as_float(e0.y) * x0;
        acc += __int_as_float(e1.y) * x1;
        acc += __int_as_float(e2.y) * x2;
        acc += __int_as_float(e3.y) * x3;
    }
    for (; i < e; ++i) {
        int2 ee = sg.eg[i];
        acc += __int_as_float(ee.y) * X[(size_t)ee.x * 64 + d];
    }
    size_t o = (size_t)lr * 64 + d;
    if (sg.a0) acc += sg.a0[o];
    if (sg.a1) acc += sg.a1[o];
    sg.out[o] = acc;
}

// ===========================================================================
// Key = E @ K in (H,N,DH) layout — register-K + scalar-E formulation.
// Round-8 lesson: per-lane scalar loads of a wave-uniform row = 64 VMEM
// instrs + 64 addr calcs per row (key3 ran 9x off roofline, VALUBusy 29%).
// Now: lane j holds K column j in 64 VGPRs (loaded once per segment);
// the row pointer is made wave-uniform via readfirstlane so E-row loads
// become s_load into SGPRs; inner loop = 64 pure v_fmac (SGPR x VGPR).
// ===========================================================================
struct KSeg { const float* E; const float* K; float* Kout; int N; };
struct Key3Args { KSeg s0, s1, s2; int n0, n01, total; };

__global__ __launch_bounds__(256) void key3(Key3Args A) {
    int nw = (gridDim.x * 256) >> 6;
    int w  = (blockIdx.x * 256 + threadIdx.x) >> 6;
    int j  = threadIdx.x & 63;
    int chunk = (A.total + nw - 1) / nw;
    int r0 = w * chunk;
    int r1 = r0 + chunk; if (r1 > A.total) r1 = A.total;

    float Kreg[64];
    int curseg = -1;
    for (int r = r0; r < r1; ++r) {
        int seg = (r < A.n0) ? 0 : ((r < A.n01) ? 1 : 2);
        KSeg sg = (seg == 0) ? A.s0 : ((seg == 1) ? A.s1 : A.s2);
        int lr = r - ((seg == 0) ? 0 : ((seg == 1) ? A.n0 : A.n01));
        if (seg != curseg) {
            curseg = seg;
#pragma unroll
            for (int kk = 0; kk < 64; ++kk) Kreg[kk] = sg.K[kk * 64 + j];
        }
        int nu = __builtin_amdgcn_readfirstlane(lr);
        const float* Er = sg.E + (size_t)nu * 64;
        float acc = 0.f;
#pragma unroll
        for (int kk = 0; kk < 64; ++kk) acc += Er[kk] * Kreg[kk];
        int h = j >> 4, dh = j & 15;
        sg.Kout[((size_t)h * sg.N + nu) * 16 + dh] = acc;
    }
}

// ===========================================================================
// A^T B partials for all 3 graphs in one dispatch. No atomics (round-2
// lesson: contended float atomics serialize the L2 RMW pipe).
// ===========================================================================
__global__ __launch_bounds__(256) void atb3(const float* __restrict__ c0, const float* __restrict__ c1, const float* __restrict__ c2,
                                            const float* __restrict__ K0, const float* __restrict__ K1, const float* __restrict__ K2,
                                            int N0, int N1, int N2,
                                            float* __restrict__ part) {
    int kidx = blockIdx.x / ATB_B;
    int lb = blockIdx.x % ATB_B;
    const float* cur = (kidx == 0) ? c0 : (kidx == 1 ? c1 : c2);
    const float* Key = (kidx == 0) ? K0 : (kidx == 1 ? K1 : K2);
    int N = (kidx == 0) ? N0 : (kidx == 1 ? N1 : N2);
    int chunk = (N + ATB_B - 1) / ATB_B;
    int tid = threadIdx.x;
    int k = tid & 63, h = tid >> 6;
    const float* Kh = Key + (size_t)h * N * 16;
    float acc[16];
#pragma unroll
    for (int i = 0; i < 16; ++i) acc[i] = 0.f;
    int s = lb * chunk;
    int e = s + chunk;
    if (e > N) e = N;
#pragma unroll 2
    for (int n = s; n < e; ++n) {
        float c = cur[(size_t)n * 64 + k];
        const float4* kr = (const float4*)(Kh + (size_t)n * 16);
        float4 k0 = kr[0], k1 = kr[1], k2 = kr[2], k3 = kr[3];
        acc[0]  += c * k0.x;  acc[1]  += c * k0.y;  acc[2]  += c * k0.z;  acc[3]  += c * k0.w;
        acc[4]  += c * k1.x;  acc[5]  += c * k1.y;  acc[6]  += c * k1.z;  acc[7]  += c * k1.w;
        acc[8]  += c * k2.x;  acc[9]  += c * k2.y;  acc[10] += c * k2.z;  acc[11] += c * k2.w;
        acc[12] += c * k3.x;  acc[13] += c * k3.y;  acc[14] += c * k3.z;  acc[15] += c * k3.w;
    }
    float4* po = (float4*)(part + ((size_t)kidx * ATB_B + lb) * 4096 + k * 64 + h * 16);
    po[0] = make_float4(acc[0],  acc[1],  acc[2],  acc[3]);
    po[1] = make_float4(acc[4],  acc[5],  acc[6],  acc[7]);
    po[2] = make_float4(acc[8],  acc[9],  acc[10], acc[11]);
    po[3] = make_float4(acc[12], acc[13], acc[14], acc[15]);
}

// Mall[k][i] = sum_b part[k][b][i]  — grid 3*16 blocks
__global__ __launch_bounds__(256) void reduce3(const float* __restrict__ part,
                                               float* __restrict__ Mall) {
    int k = blockIdx.x >> 4;
    int i = (blockIdx.x & 15) * 256 + threadIdx.x;
    const float* p = part + (size_t)k * ATB_B * 4096 + i;
    float s = 0.f;
#pragma unroll 8
    for (int b = 0; b < ATB_B; ++b) s += p[(size_t)b * 4096];
    Mall[k * 4096 + i] = s;
}

// ===========================================================================
// Entire small chain VK->t1->ff->ff->pre0->pre2 in ONE kernel.
// One 1024-thread workgroup per graph; ALL stage operands LDS-staged with
// coalesced global loads (round-4 lesson). W chunks stored transposed with
// stride 129 (2-way bank alias = free).
// ===========================================================================
__global__ __launch_bounds__(1024) void chain3(const float* __restrict__ Mall,
                                               const float* __restrict__ pV,
                                               const float* __restrict__ hyp3,
                                               const float* __restrict__ W1,
                                               const float* __restrict__ W2,
                                               const float* __restrict__ Vt,
                                               float* __restrict__ pre2all, int l) {
    int kg = blockIdx.x;
    const float* M    = Mall + kg * 4096;
    const float* pVk  = pV + kg * 4096;
    const float* hyp  = hyp3 + kg * 8192;
    const float* W1kl = W1 + (size_t)(kg * 2 + l) * 16384;
    const float* W2kl = W2 + (size_t)(kg * 2 + l) * 16384;
    const float* Vk   = Vt + kg * 4096;
    float* pre2 = pre2all + kg * 1024;

    __shared__ float tA[8192];
    __shared__ float tB[8192];
    __shared__ float hypsh[8192];
    __shared__ float shW[64 * 129 + 64];   // reused: M+pV -> W chunks -> V
    __shared__ float VKs[1024];

    int tid = threadIdx.x;
    for (int i = tid; i < 8192; i += 1024) hypsh[i] = hyp[i];
    for (int i = tid; i < 4096; i += 1024) { shW[i] = M[i]; shW[4096 + i] = pVk[i]; }
    __syncthreads();

    // VK[h,d1,d2] = sum_k pV[k,h*16+d1] * M[k,h*16+d2]
    {
        int d2 = tid & 15, d1 = (tid >> 4) & 15, h = tid >> 8;
        float s = 0.f;
#pragma unroll
        for (int k2 = 0; k2 < 64; ++k2)
            s += shW[4096 + k2 * 64 + h * 16 + d1] * shW[k2 * 64 + h * 16 + d2];
        VKs[tid] = s;
    }
    __syncthreads();

    // t1[d,m] -> tA
    for (int i = tid; i < 8192; i += 1024) {
        int m = i & 127, d = i >> 7, h = d >> 4;
        float s = 0.f;
#pragma unroll
        for (int d2 = 0; d2 < 16; ++d2) s += VKs[d * 16 + d2] * hypsh[(h * 16 + d2) * 128 + m];
        tA[i] = s;
    }
    __syncthreads();

    // ff1: tB = leaky(tA @ W1^T) + tA
    {
        float acc[8];
#pragma unroll
        for (int j = 0; j < 8; ++j) acc[j] = 0.f;
        for (int c = 0; c < 2; ++c) {
            __syncthreads();
            for (int t = tid; t < 8192; t += 1024) {
                int m = t >> 6, mml = t & 63;
                shW[mml * 129 + m] = W1kl[m * 128 + c * 64 + mml];
            }
            __syncthreads();
#pragma unroll
            for (int j = 0; j < 8; ++j) {
                int i = tid + j * 1024;
                int m = i & 127, d = i >> 7;
                const float* tr = tA + d * 128 + c * 64;
                float s = 0.f;
#pragma unroll
                for (int mm = 0; mm < 64; ++mm) s += tr[mm] * shW[mm * 129 + m];
                acc[j] += s;
            }
        }
#pragma unroll
        for (int j = 0; j < 8; ++j) {
            int i = tid + j * 1024;
            float s = acc[j];
            tB[i] = (s >= 0.f ? s : 0.5f * s) + tA[i];
        }
    }
    __syncthreads();

    // ff2: tA = leaky(tB @ W2^T) + tB
    {
        float acc[8];
#pragma unroll
        for (int j = 0; j < 8; ++j) acc[j] = 0.f;
        for (int c = 0; c < 2; ++c) {
            __syncthreads();
            for (int t = tid; t < 8192; t += 1024) {
                int m = t >> 6, mml = t & 63;
                shW[mml * 129 + m] = W2kl[m * 128 + c * 64 + mml];
            }
            __syncthreads();
#pragma unroll
            for (int j = 0; j < 8; ++j) {
                int i = tid + j * 1024;
                int m = i & 127, d = i >> 7;
                const float* tr = tB + d * 128 + c * 64;
                float s = 0.f;
#pragma unroll
                for (int mm = 0; mm < 64; ++mm) s += tr[mm] * shW[mm * 129 + m];
                acc[j] += s;
            }
        }
#pragma unroll
        for (int j = 0; j < 8; ++j) {
            int i = tid + j * 1024;
            float s = acc[j];
            tA[i] = (s >= 0.f ? s : 0.5f * s) + tB[i];
        }
    }
    __syncthreads();

    for (int i = tid; i < 4096; i += 1024) shW[i] = Vk[i];
    __syncthreads();

    // pre0[m,dd] -> tB
    for (int i = tid; i < 8192; i += 1024) {
        int dd = i & 63, m = i >> 6;
        float s = 0.f;
#pragma unroll
        for (int d = 0; d < 64; ++d) s += tA[d * 128 + m] * shW[d * 64 + dd];
        tB[i] = s;
    }
    __syncthreads();

    // pre2[h,d1,d2]
    {
        int d2 = tid & 15, d1 = (tid >> 4) & 15, h = tid >> 8;
        float s = 0.f;
#pragma unroll
        for (int m = 0; m < 128; ++m)
            s += hypsh[(h * 16 + d1) * 128 + m] * tB[m * 64 + h * 16 + d2];
        pre2[tid] = s;
    }
}

// ===========================================================================
// Expand (Key @ pre2), 3 segments, one dispatch.
// ===========================================================================
struct ESeg { const float* Key; const float* pre2; const float* in; float* out1; float* out2; int N; };
struct Exp3Args { ESeg s0, s1, s2; int b1, b2; };

__global__ __launch_bounds__(256) void expand3(Exp3Args A, int mode) {
    int b = blockIdx.x;
    ESeg sg; int lb;
    if (b >= A.b2)      { sg = A.s2; lb = b - A.b2; }
    else if (b >= A.b1) { sg = A.s1; lb = b - A.b1; }
    else                { sg = A.s0; lb = b; }
    __shared__ float p2[1024];
    int tid = threadIdx.x;
    for (int i = tid; i < 1024; i += 256) p2[i] = sg.pre2[i];
    __syncthreads();
    int j = tid & 63, slot = tid >> 6;
    int n = lb * 4 + slot;
    if (n >= sg.N) return;
    int h = j >> 4, d2 = j & 15;
    const float* kr = sg.Key + ((size_t)h * sg.N + n) * 16;
    float s = 0.f;
#pragma unroll
    for (int d1 = 0; d1 < 16; ++d1) s += kr[d1] * p2[(h * 16 + d1) * 16 + d2];
    size_t o = (size_t)n * 64 + j;
    if (mode == 0) { sg.out1[o] = s; sg.out2[o] = sg.in[o] + s; }
    else           { sg.out1[o] = sg.in[o] + s; }
}

// ---------------------------------------------------------------------------
// Build hyp3[k][h,dh,m] = Hyper[k][m, h*16+dh] and copy Hyper -> out
// ---------------------------------------------------------------------------
__global__ __launch_bounds__(256) void hyp_kernel(const float* __restrict__ Hyper,
                                                  float* __restrict__ hyp3,
                                                  float* __restrict__ out,
                                                  size_t off0, size_t off1, size_t off2) {
    int i = blockIdx.x * 256 + threadIdx.x;
    if (i >= 3 * 8192) return;
    int k = i / 8192, r = i % 8192;
    float v = Hyper[i];
    size_t off = (k == 0) ? off0 : ((k == 1) ? off1 : off2);
    out[off + r] = v;
    int m = r >> 6, dcol = r & 63;
    hyp3[k * 8192 + dcol * 128 + m] = v;
}

// ===========================================================================
// FALLBACK kernels (atomic-scatter path, used only if ws too small)
// ===========================================================================
__global__ __launch_bounds__(256) void spmm_k(const int* __restrict__ rows,
                                              const int* __restrict__ cols,
                                              const float* __restrict__ vals,
                                              const float* __restrict__ X,
                                              float* __restrict__ out, int nnz) {
    int gid = blockIdx.x * 256 + threadIdx.x;
    int e = gid >> 6;
    if (e >= nnz) return;
    int d = gid & 63;
    int r = rows[e], c = cols[e];
    float v = vals[e];
    atomicAdd(&out[(size_t)r * 64 + d], v * X[(size_t)c * 64 + d]);
}

__global__ __launch_bounds__(256) void add3_kernel(const float* __restrict__ base,
                                                   const float* __restrict__ a,
                                                   const float* __restrict__ b,
                                                   float* __restrict__ outb, size_t n) {
    size_t i = (size_t)blockIdx.x * 256 + threadIdx.x;
    if (i >= n) return;
    outb[i] = base[i] + a[i] + b[i];
}

__global__ __launch_bounds__(256) void key_gemm(const float* __restrict__ E,
                                                const float* __restrict__ K,
                                                float* __restrict__ Kout, int N) {
    __shared__ float Ksh[4096];
    int tid = threadIdx.x;
    for (int i = tid; i < 4096; i += 256) Ksh[i] = K[i];
    __syncthreads();
    int j = tid & 63, slot = tid >> 6;
    int n = blockIdx.x * 4 + slot;
    if (n >= N) return;
    const float* Er = E + (size_t)n * 64;
    float acc = 0.f;
#pragma unroll
    for (int kk = 0; kk < 64; ++kk) acc += Er[kk] * Ksh[kk * 64 + j];
    int h = j >> 4, dh = j & 15;
    Kout[((size_t)h * N + n) * 16 + dh] = acc;
}

#define ATB_ROWS 128
__global__ __launch_bounds__(256) void atb_k(const float* __restrict__ cur,
                                             const float* __restrict__ Key,
                                             float* __restrict__ M, int N) {
    int tid = threadIdx.x;
    int k = tid & 63, h = tid >> 6;
    const float* Kh = Key + (size_t)h * N * 16;
    float acc[16];
#pragma unroll
    for (int i = 0; i < 16; ++i) acc[i] = 0.f;
    int s = blockIdx.x * ATB_ROWS;
    int e = s + ATB_ROWS;
    if (e > N) e = N;
    for (int n = s; n < e; ++n) {
        float c = cur[(size_t)n * 64 + k];
        const float4* kr = (const float4*)(Kh + (size_t)n * 16);
        float4 k0 = kr[0], k1 = kr[1], k2 = kr[2], k3 = kr[3];
        acc[0]  += c * k0.x;  acc[1]  += c * k0.y;  acc[2]  += c * k0.z;  acc[3]  += c * k0.w;
        acc[4]  += c * k1.x;  acc[5]  += c * k1.y;  acc[6]  += c * k1.z;  acc[7]  += c * k1.w;
        acc[8]  += c * k2.x;  acc[9]  += c * k2.y;  acc[10] += c * k2.z;  acc[11] += c * k2.w;
        acc[12] += c * k3.x;  acc[13] += c * k3.y;  acc[14] += c * k3.z;  acc[15] += c * k3.w;
    }
#pragma unroll
    for (int d2 = 0; d2 < 16; ++d2)
        atomicAdd(&M[k * 64 + h * 16 + d2], acc[d2]);
}

__global__ __launch_bounds__(256) void vk_small(const float* __restrict__ M,
                                                const float* __restrict__ pV,
                                                float* __restrict__ VK) {
    int i = blockIdx.x * 256 + threadIdx.x;
    if (i >= 1024) return;
    int d2 = i & 15, d1 = (i >> 4) & 15, h = i >> 8;
    float s = 0.f;
#pragma unroll
    for (int k = 0; k < 64; ++k)
        s += pV[k * 64 + h * 16 + d1] * M[k * 64 + h * 16 + d2];
    VK[i] = s;
}

__global__ __launch_bounds__(256) void t1_kernel(const float* __restrict__ VK,
                                                 const float* __restrict__ hyp,
                                                 float* __restrict__ t1) {
    int i = blockIdx.x * 256 + threadIdx.x;
    if (i >= 8192) return;
    int m = i & 127, d = i >> 7, h = d >> 4;
    float s = 0.f;
#pragma unroll
    for (int d2 = 0; d2 < 16; ++d2) s += VK[d * 16 + d2] * hyp[(h * 16 + d2) * 128 + m];
    t1[i] = s;
}

__global__ __launch_bounds__(256) void ff_kernel(const float* __restrict__ tin,
                                                 const float* __restrict__ W,
                                                 float* __restrict__ tout) {
    int i = blockIdx.x * 256 + threadIdx.x;
    if (i >= 8192) return;
    int m = i & 127, d = i >> 7;
    const float* tr = tin + d * 128;
    const float* wr = W + m * 128;
    float s = 0.f;
#pragma unroll
    for (int mm = 0; mm < 128; ++mm) s += tr[mm] * wr[mm];
    tout[i] = (s >= 0.f ? s : 0.5f * s) + tin[i];
}

__global__ __launch_bounds__(256) void pre0_kernel(const float* __restrict__ t3,
                                                   const float* __restrict__ V,
                                                   float* __restrict__ pre0) {
    int i = blockIdx.x * 256 + threadIdx.x;
    if (i >= 8192) return;
    int dd = i & 63, m = i >> 6;
    float s = 0.f;
#pragma unroll
    for (int d = 0; d < 64; ++d) s += t3[d * 128 + m] * V[d * 64 + dd];
    pre0[m * 64 + dd] = s;
}

__global__ __launch_bounds__(256) void pre2_kernel(const float* __restrict__ hyp,
                                                   const float* __restrict__ pre0,
                                                   float* __restrict__ pre2) {
    int i = blockIdx.x * 256 + threadIdx.x;
    if (i >= 1024) return;
    int d2 = i & 15, d1 = (i >> 4) & 15, h = i >> 8;
    float s = 0.f;
#pragma unroll
    for (int m = 0; m < 128; ++m) s += hyp[(h * 16 + d1) * 128 + m] * pre0[m * 64 + h * 16 + d2];
    pre2[i] = s;
}

__global__ __launch_bounds__(256) void expand0_kernel(const float* __restrict__ Key,
                                                      const float* __restrict__ pre2,
                                                      const float* __restrict__ E0,
                                                      float* __restrict__ nxt,
                                                      float* __restrict__ tot, int N) {
    __shared__ float p2[1024];
    int tid = threadIdx.x;
    for (int i = tid; i < 1024; i += 256) p2[i] = pre2[i];
    __syncthreads();
    int j = tid & 63, slot = tid >> 6;
    int n = blockIdx.x * 4 + slot;
    if (n >= N) return;
    int h = j >> 4, d2 = j & 15;
    const float* kr = Key + ((size_t)h * N + n) * 16;
    float s = 0.f;
#pragma unroll
    for (int d1 = 0; d1 < 16; ++d1) s += kr[d1] * p2[(h * 16 + d1) * 16 + d2];
    size_t o = (size_t)n * 64 + j;
    nxt[o] = s;
    tot[o] = E0[o] + s;
}

__global__ __launch_bounds__(256) void expand1_kernel(const float* __restrict__ Key,
                                                      const float* __restrict__ pre2,
                                                      const float* __restrict__ tot,
                                                      float* __restrict__ outb, int N) {
    __shared__ float p2[1024];
    int tid = threadIdx.x;
    for (int i = tid; i < 1024; i += 256) p2[i] = pre2[i];
    __syncthreads();
    int j = tid & 63, slot = tid >> 6;
    int n = blockIdx.x * 4 + slot;
    if (n >= N) return;
    int h = j >> 4, d2 = j & 15;
    const float* kr = Key + ((size_t)h * N + n) * 16;
    float s = 0.f;
#pragma unroll
    for (int d1 = 0; d1 < 16; ++d1) s += kr[d1] * p2[(h * 16 + d1) * 16 + d2];
    size_t o = (size_t)n * 64 + j;
    outb[o] = tot[o] + s;
}

// ===========================================================================
extern "C" void kernel_launch(void* const* d_in, const int* in_sizes, int n_in,
                              void* d_out, int out_size, void* d_ws, size_t ws_size,
                              hipStream_t stream) {
    const float* uE      = (const float*)d_in[0];
    const float* iE      = (const float*)d_in[1];
    const float* Ks      = (const float*)d_in[2];
    const float* Hyper   = (const float*)d_in[3];
    const float* Vt      = (const float*)d_in[4];
    const float* pV      = (const float*)d_in[5];
    const float* W1      = (const float*)d_in[6];
    const float* W2      = (const float*)d_in[7];
    const int* adj_rows  = (const int*)d_in[8];
    const int* adj_cols  = (const int*)d_in[9];
    const float* adj_vals= (const float*)d_in[10];
    const int* tp_rows   = (const int*)d_in[11];
    const int* tp_cols   = (const int*)d_in[12];
    const float* tp_vals = (const float*)d_in[13];
    const int* uu_rows   = (const int*)d_in[14];
    const int* uu_cols   = (const int*)d_in[15];
    const float* uu_vals = (const float*)d_in[16];

    const int U = in_sizes[0] / 64;
    const int I = in_sizes[1] / 64;
    const int nnz_ui = in_sizes[8];
    const int nnz_uu = in_sizes[14];
    const size_t UD = (size_t)U * 64, ID = (size_t)I * 64;

    float* out = (float*)d_out;
    const size_t o_uE0 = 0;
    const size_t o_iE0 = UD;
    const size_t o_ulat = UD + ID;
    const size_t o_ilat = 2 * UD + ID;
    const size_t o_uKey = 2 * UD + 2 * ID;
    const size_t o_iKey = 3 * UD + 2 * ID;
    const size_t o_uHyp = 3 * UD + 3 * ID;
    const size_t o_iHyp = o_uHyp + 8192;
    const size_t o_uuE0 = o_iHyp + 8192;
    const size_t o_uulat = o_uuE0 + UD;
    const size_t o_uuKey = o_uulat + UD;
    const size_t o_uuHyp = o_uuKey + UD;

    // ---- new-path ws layout ----
    float* ws   = (float*)d_ws;
    float* B1   = ws;               // UD: h1u -> nxt_u
    float* B2   = B1 + UD;          // ID: h1i -> nxt_i
    float* B3   = B2 + ID;          // UD: tot_u
    float* Ti   = B3 + UD;          // ID: tot_i
    float* Buu1 = Ti + ID;          // UD: h1uu -> nxt_uu
    float* Tuu  = Buu1 + UD;        // UD: tot_uu
    float* hyp3 = Tuu + UD;              // 24576
    float* Mall = hyp3 + 24576;          // 12288
    float* pre2all = Mall + 12288;       // 3072
    int2*  edge_a = (int2*)(pre2all + 3072);
    int2*  edge_t = edge_a + nnz_ui;
    int2*  edge_u = edge_t + nnz_ui;
    int*   rpAll  = (int*)(edge_u + nnz_uu);          // (U+1)+(I+1)+(U+1)
    int*   curAll = rpAll + (U + 1) + (I + 1) + (U + 1);
    int*   bsumAll= curAll + U + I + U;               // 3*1024
    float* partw  = (float*)(bsumAll + 3072);         // 3*ATB_B*4096
    size_t need_bytes = (size_t)((char*)(partw + (size_t)3 * ATB_B * 4096) - (char*)d_ws);
    const int nbA = (U + 255) / 256, nbT = (I + 255) / 256, nbU = (U + 255) / 256;
    const bool use_new = (ws_size >= need_bytes) && (nbA <= 1024) && (nbT <= 1024);

    int* rp_a = rpAll;
    int* rp_t = rpAll + (U + 1);
    int* rp_u = rpAll + (U + 1) + (I + 1);

    if (use_new) {
        // ---- CSR build for all 3 graphs ----
        hipMemsetAsync(curAll, 0, (size_t)(U + I + U) * sizeof(int), stream);
        int totE = 2 * nnz_ui + nnz_uu;
        hist3<<<(totE + 255) / 256, 256, 0, stream>>>(adj_rows, tp_rows, uu_rows,
                                                      nnz_ui, nnz_uu, curAll, U, I);
        scan_part3<<<nbA + nbT + nbU, 256, 0, stream>>>(curAll, bsumAll, U, I, nbA, nbT);
        scan_top3<<<3, 1024, 0, stream>>>(bsumAll, nbA, nbT, nbU);
        scan_final3<<<nbA + nbT + nbU, 256, 0, stream>>>(curAll, bsumAll, rpAll,
                                                         U, I, nbA, nbT, nnz_ui, nnz_uu);
        // Row-range-filtered scatters: dest region ~4MB per pass (L2-resident
        // writes), full-occupancy grids (round-7 lesson).
        const int gSa = (nnz_ui + 255) / 256;
        const int gSu = (nnz_uu + 255) / 256;
        const int hU = (U + 1) / 2, hI = (I + 1) / 2;
        scatter_r<<<gSa, 256, 0, stream>>>(adj_rows, adj_cols, adj_vals, curAll,         edge_a, nnz_ui, 0,  hU);
        scatter_r<<<gSa, 256, 0, stream>>>(adj_rows, adj_cols, adj_vals, curAll,         edge_a, nnz_ui, hU, U);
        scatter_r<<<gSa, 256, 0, stream>>>(tp_rows,  tp_cols,  tp_vals,  curAll + U,     edge_t, nnz_ui, 0,  hI);
        scatter_r<<<gSa, 256, 0, stream>>>(tp_rows,  tp_cols,  tp_vals,  curAll + U,     edge_t, nnz_ui, hI, I);
        scatter_r<<<gSu, 256, 0, stream>>>(uu_rows,  uu_cols,  uu_vals,  curAll + U + I, edge_u, nnz_uu, 0,  hU);
        scatter_r<<<gSu, 256, 0, stream>>>(uu_rows,  uu_cols,  uu_vals,  curAll + U + I, edge_u, nnz_uu, hU, U);

        // ---- gather SpMM phases (3 dispatches) ----
        // S1: B2 = A^T.uE ; B1 = A.iE
        {
            Spmm3Args A;
            A.s0 = { rp_t, edge_t, uE, nullptr, nullptr, B2, I };
            A.s1 = { rp_a, edge_a, iE, nullptr, nullptr, B1, U };
            A.s2 = { nullptr, nullptr, nullptr, nullptr, nullptr, nullptr, 0 };
            A.n0 = I; A.n01 = I + U; A.total = I + U;
            spmm3<<<(int)(((size_t)A.total * 64 + 255) / 256), 256, 0, stream>>>(A);
        }
        // S2: uE0 = uE+B1+A.B2 ; iE0 = iE+B2+A^T.B1 ; Buu1 = Buu.uE
        {
            Spmm3Args A;
            A.s0 = { rp_a, edge_a, B2, uE, B1, out + o_uE0, U };
            A.s1 = { rp_t, edge_t, B1, iE, B2, out + o_iE0, I };
            A.s2 = { rp_u, edge_u, uE, nullptr, nullptr, Buu1, U };
            A.n0 = U; A.n01 = U + I; A.total = U + I + U;
            spmm3<<<(int)(((size_t)A.total * 64 + 255) / 256), 256, 0, stream>>>(A);
        }
        // S3: uuE0 = uE + Buu1 + Buu.Buu1
        {
            Spmm3Args A;
            A.s0 = { rp_u, edge_u, Buu1, uE, Buu1, out + o_uuE0, U };
            A.s1 = { nullptr, nullptr, nullptr, nullptr, nullptr, nullptr, 0 };
            A.s2 = A.s1;
            A.n0 = U; A.n01 = U; A.total = U;
            spmm3<<<(int)(((size_t)A.total * 64 + 255) / 256), 256, 0, stream>>>(A);
        }

        hyp_kernel<<<(3 * 8192 + 255) / 256, 256, 0, stream>>>(Hyper, hyp3, out,
                                                               o_uHyp, o_iHyp, o_uuHyp);

        // ---- keys for all 3 graphs (1 dispatch, register-K scalar-E) ----
        {
            Key3Args A;
            A.s0 = { out + o_uE0,  Ks,        out + o_uKey,  U };
            A.s1 = { out + o_iE0,  Ks + 4096, out + o_iKey,  I };
            A.s2 = { out + o_uuE0, Ks + 8192, out + o_uuKey, U };
            A.n0 = U; A.n01 = U + I; A.total = U + I + U;
            key3<<<2048, 256, 0, stream>>>(A);
        }

        const float* Key0 = out + o_uKey;
        const float* Key1 = out + o_iKey;
        const float* Key2 = out + o_uuKey;
        const int gb0 = (U + 3) / 4, gb1 = (I + 3) / 4, gb2 = (U + 3) / 4;

        for (int l = 0; l < 2; ++l) {
            const float* c0 = (l == 0) ? (out + o_uE0)  : B1;
            const float* c1 = (l == 0) ? (out + o_iE0)  : B2;
            const float* c2 = (l == 0) ? (out + o_uuE0) : Buu1;

            atb3<<<3 * ATB_B, 256, 0, stream>>>(c0, c1, c2, Key0, Key1, Key2, U, I, U, partw);
            reduce3<<<48, 256, 0, stream>>>(partw, Mall);
            chain3<<<3, 1024, 0, stream>>>(Mall, pV, hyp3, W1, W2, Vt, pre2all, l);

            Exp3Args E;
            E.b1 = gb0; E.b2 = gb0 + gb1;
            if (l == 0) {
                E.s0 = { Key0, pre2all,        out + o_uE0,  B1,   B3,  U };
                E.s1 = { Key1, pre2all + 1024, out + o_iE0,  B2,   Ti,  I };
                E.s2 = { Key2, pre2all + 2048, out + o_uuE0, Buu1, Tuu, U };
                expand3<<<gb0 + gb1 + gb2, 256, 0, stream>>>(E, 0);
            } else {
                E.s0 = { Key0, pre2all,        B3,  out + o_ulat,  nullptr, U };
                E.s1 = { Key1, pre2all + 1024, Ti,  out + o_ilat,  nullptr, I };
                E.s2 = { Key2, pre2all + 2048, Tuu, out + o_uulat, nullptr, U };
                expand3<<<gb0 + gb1 + gb2, 256, 0, stream>>>(E, 1);
            }
        }
    } else {
        // ---- fallback: original atomic-scatter path (round-0 structure) ----
        float* fB1 = ws;
        float* fB2 = fB1 + UD;
        float* fB3 = fB2 + ID;
        float* fhyp3 = fB2;
        float* fVK  = fhyp3 + 3 * 8192;
        float* ft1  = fVK + 1024;
        float* ft2  = ft1 + 8192;
        float* ft3  = ft2 + 8192;
        float* fpre0 = ft3 + 8192;
        float* fpre2 = fpre0 + 8192;
        float* fM   = fpre2 + 1024;

        const int g_ui = (int)(((size_t)nnz_ui * 64 + 255) / 256);
        const int g_uu = (int)(((size_t)nnz_uu * 64 + 255) / 256);
        const int gU = (int)((UD + 255) / 256);
        const int gI = (int)((ID + 255) / 256);
        hipMemsetAsync(fB1, 0, UD * sizeof(float), stream);
        spmm_k<<<g_ui, 256, 0, stream>>>(adj_rows, adj_cols, adj_vals, iE, fB1, nnz_ui);
        hipMemsetAsync(fB2, 0, ID * sizeof(float), stream);
        spmm_k<<<g_ui, 256, 0, stream>>>(tp_rows, tp_cols, tp_vals, uE, fB2, nnz_ui);
        hipMemsetAsync(fB3, 0, UD * sizeof(float), stream);
        spmm_k<<<g_ui, 256, 0, stream>>>(adj_rows, adj_cols, adj_vals, fB2, fB3, nnz_ui);
        add3_kernel<<<gU, 256, 0, stream>>>(uE, fB1, fB3, out + o_uE0, UD);
        hipMemsetAsync(fB3, 0, ID * sizeof(float), stream);
        spmm_k<<<g_ui, 256, 0, stream>>>(tp_rows, tp_cols, tp_vals, fB1, fB3, nnz_ui);
        add3_kernel<<<gI, 256, 0, stream>>>(iE, fB2, fB3, out + o_iE0, ID);
        hipMemsetAsync(fB1, 0, UD * sizeof(float), stream);
        spmm_k<<<g_uu, 256, 0, stream>>>(uu_rows, uu_cols, uu_vals, uE, fB1, nnz_uu);
        hipMemsetAsync(fB3, 0, UD * sizeof(float), stream);
        spmm_k<<<g_uu, 256, 0, stream>>>(uu_rows, uu_cols, uu_vals, fB1, fB3, nnz_uu);
        add3_kernel<<<gU, 256, 0, stream>>>(uE, fB1, fB3, out + o_uuE0, UD);

        hyp_kernel<<<(3 * 8192 + 255) / 256, 256, 0, stream>>>(Hyper, fhyp3, out,
                                                               o_uHyp, o_iHyp, o_uuHyp);

        const int    Narr[3] = { U, I, U };
        const size_t oE[3]   = { o_uE0, o_iE0, o_uuE0 };
        const size_t oK[3]   = { o_uKey, o_iKey, o_uuKey };
        const size_t oL[3]   = { o_ulat, o_ilat, o_uulat };

        for (int k = 0; k < 3; ++k) {
            int N = Narr[k];
            const float* E0k = out + oE[k];
            float* Keyk = out + oK[k];
            const float* Ksk = Ks + k * 4096;
            const float* pVk = pV + k * 4096;
            const float* Vk  = Vt + k * 4096;
            const float* hypk = fhyp3 + k * 8192;

            key_gemm<<<(N + 3) / 4, 256, 0, stream>>>(E0k, Ksk, Keyk, N);

            for (int l = 0; l < 2; ++l) {
                const float* W1kl = W1 + (size_t)(k * 2 + l) * 16384;
                const float* W2kl = W2 + (size_t)(k * 2 + l) * 16384;

                hipMemsetAsync(fM, 0, 4096 * sizeof(float), stream);
                atb_k<<<(N + ATB_ROWS - 1) / ATB_ROWS, 256, 0, stream>>>(
                    (l == 0) ? E0k : fB1, Keyk, fM, N);
                vk_small<<<4, 256, 0, stream>>>(fM, pVk, fVK);
                t1_kernel<<<32, 256, 0, stream>>>(fVK, hypk, ft1);
                ff_kernel<<<32, 256, 0, stream>>>(ft1, W1kl, ft2);
                ff_kernel<<<32, 256, 0, stream>>>(ft2, W2kl, ft3);
                pre0_kernel<<<32, 256, 0, stream>>>(ft3, Vk, fpre0);
                pre2_kernel<<<4, 256, 0, stream>>>(hypk, fpre0, fpre2);

                if (l == 0) {
                    expand0_kernel<<<(N + 3) / 4, 256, 0, stream>>>(Keyk, fpre2, E0k, fB1, fB3, N);
                } else {
                    expand1_kernel<<<(N + 3) / 4, 256, 0, stream>>>(Keyk, fpre2, fB3, out + oL[k], N);
                }
            }
        }
    }
}